// Round 9
// baseline (185.227 us; speedup 1.0000x reference)
//
#include <hip/hip_runtime.h>
#include <hip/hip_bf16.h>
#include <math.h>

#define B_  2
#define L_  1024
#define D_  1024
#define H_  16
#define DH_ 64
#define M_  (B_*L_)   // 2048
#define CHUNK 64
#define NCH (L_/CHUNK)   // 16
#define PT 72   // bf16 LDS tile pad (shorts): rows 144B, 16B-aligned
#define PS 76   // f32 LDS out-stage pad (floats): rows 304B, 16B-aligned

#define KSCALE (0.02f/32.0f)   // /sqrt(D) * 0.02

using bf16x8 = __attribute__((ext_vector_type(8))) short;
using f32x4  = __attribute__((ext_vector_type(4))) float;

__device__ __forceinline__ unsigned short bf16r(float f){
  union{float f; unsigned int u;} x; x.f = f;
  unsigned int r = x.u + 0x7FFF + ((x.u>>16)&1);
  return (unsigned short)(r>>16);
}
__device__ __forceinline__ float bf2f(unsigned short u){
  union{unsigned int u; float f;} x; x.u = ((unsigned int)u)<<16; return x.f;
}

// in-wave gate prefix for chunk c of bh: cf_s/gc_s for the 64 rows. lanes 0..63.
__device__ __forceinline__ void gate_prefix(
  const float* __restrict__ GL, const float* __restrict__ RR,
  int bh, int c, int l, float* cf_s, float* gc_s)
{
  float carry = 0.f;
  for (int it = 0; it < c; ++it){
    float g = GL[(size_t)bh*L_ + it*64 + l];
    #pragma unroll
    for (int off = 32; off; off >>= 1) g += __shfl_xor(g, off);
    carry += g;
  }
  float x = GL[(size_t)bh*L_ + c*64 + l];
  #pragma unroll
  for (int off = 1; off < 64; off <<= 1){
    float t = __shfl_up(x, off);
    if (l >= off) x += t;
  }
  float cum = carry + x;
  float lc = fminf(fmaxf(cum, -30.f), 30.f);
  float gc = expf(lc) + 1e-6f;
  cf_s[l] = RR[(size_t)bh*L_ + c*64 + l] / gc;
  if (gc_s) gc_s[l] = gc;
}

// ---------------- all conversions in one launch ----------------
__global__ __launch_bounds__(256) void convert_all(
  const float* __restrict__ X,
  const float* __restrict__ W0, const float* __restrict__ W1,
  const float* __restrict__ W2, const float* __restrict__ W3,
  unsigned short* __restrict__ Xbf,
  unsigned short* __restrict__ T0, unsigned short* __restrict__ T1,
  unsigned short* __restrict__ T2, unsigned short* __restrict__ T3)
{
  int z = blockIdx.z;
  if (z == 4) {
    int row = blockIdx.x*64 + (threadIdx.x>>2);
    int col = blockIdx.y*64 + (threadIdx.x&3)*16;
    const float4* src = (const float4*)&X[(size_t)row*D_ + col];
    float4 a=src[0], b=src[1], c=src[2], d=src[3];
    unsigned short buf[16] = {
      bf16r(a.x),bf16r(a.y),bf16r(a.z),bf16r(a.w),
      bf16r(b.x),bf16r(b.y),bf16r(b.z),bf16r(b.w),
      bf16r(c.x),bf16r(c.y),bf16r(c.z),bf16r(c.w),
      bf16r(d.x),bf16r(d.y),bf16r(d.z),bf16r(d.w)};
    *(uint4*)&Xbf[(size_t)row*D_ + col]     = *(uint4*)&buf[0];
    *(uint4*)&Xbf[(size_t)row*D_ + col + 8] = *(uint4*)&buf[8];
    return;
  }
  if (blockIdx.x >= 16) return;
  const float* W = z==0?W0: z==1?W1: z==2?W2: W3;
  unsigned short* T = z==0?T0: z==1?T1: z==2?T2: T3;
  __shared__ float tile[64][65];
  int kBase = blockIdx.x*64, nBase = blockIdx.y*64;
  #pragma unroll
  for (int i=0;i<16;i++){
    int idx = threadIdx.x + i*256;
    int r = idx>>6, c = idx&63;
    tile[r][c] = W[(size_t)(kBase+r)*D_ + nBase+c];
  }
  __syncthreads();
  #pragma unroll
  for (int i=0;i<16;i++){
    int idx = threadIdx.x + i*256;
    int n = idx>>6, k = idx&63;
    T[(size_t)(nBase+n)*D_ + kBase+k] = bf16r(tile[k][n]);
  }
}

// ---------------- 128x128 MFMA GEMM (bf16 out): 3 projections ----------------
__global__ __launch_bounds__(256) void gemm3(
  const unsigned short* __restrict__ A,
  const unsigned short* __restrict__ T0, const unsigned short* __restrict__ T1,
  const unsigned short* __restrict__ T2,
  const float* __restrict__ b0, const float* __restrict__ b1, const float* __restrict__ b2,
  unsigned short* __restrict__ F0, unsigned short* __restrict__ F1,
  unsigned short* __restrict__ F2)
{
  int z = blockIdx.z;
  const unsigned short* Bt = z==0?T0: z==1?T1: T2;
  const float* bias = z==0?b0: z==1?b1: b2;
  unsigned short* F = z==0?F0: z==1?F1: F2;
  int epi = (z==2) ? 1 : 0;
  int rowBase = blockIdx.x*128, colBase = blockIdx.y*128;

  __shared__ __align__(16) unsigned short As[128*32];
  __shared__ __align__(16) unsigned short Bs[128*32];
  int tid = threadIdx.x, w = tid>>6, l = tid&63;
  int lr = l&15, g4 = l>>4;
  int wr = w>>1, wc = w&1;
  f32x4 acc[4][4];
  #pragma unroll
  for (int mi=0;mi<4;mi++)
    #pragma unroll
    for (int ni=0;ni<4;ni++)
      acc[mi][ni] = (f32x4){0.f,0.f,0.f,0.f};

  for (int k0 = 0; k0 < D_; k0 += 32) {
    #pragma unroll
    for (int i=0;i<2;i++){
      int Fi = (w*2+i)*64 + l;
      int r = Fi>>2, c16 = Fi&3;
      int sc = c16 ^ ((r>>1)&3);
      const unsigned short* ga = A  + (size_t)(rowBase+r)*D_ + k0 + sc*8;
      const unsigned short* gb = Bt + (size_t)(colBase+r)*D_ + k0 + sc*8;
      __builtin_amdgcn_global_load_lds(
        (const __attribute__((address_space(1))) void*)ga,
        (__attribute__((address_space(3))) void*)(As + (size_t)(w*2+i)*512), 16, 0, 0);
      __builtin_amdgcn_global_load_lds(
        (const __attribute__((address_space(1))) void*)gb,
        (__attribute__((address_space(3))) void*)(Bs + (size_t)(w*2+i)*512), 16, 0, 0);
    }
    __syncthreads();
    bf16x8 af[4], bfr[4];
    #pragma unroll
    for (int mi=0;mi<4;mi++){
      int row = wr*64 + mi*16 + lr;
      af[mi] = *(const bf16x8*)(As + row*32 + ((g4 ^ ((row>>1)&3))*8));
    }
    #pragma unroll
    for (int ni=0;ni<4;ni++){
      int n = wc*64 + ni*16 + lr;
      bfr[ni] = *(const bf16x8*)(Bs + n*32 + ((g4 ^ ((n>>1)&3))*8));
    }
    #pragma unroll
    for (int mi=0;mi<4;mi++)
      #pragma unroll
      for (int ni=0;ni<4;ni++)
        acc[mi][ni] = __builtin_amdgcn_mfma_f32_16x16x32_bf16(af[mi], bfr[ni], acc[mi][ni], 0,0,0);
    __syncthreads();
  }

  #pragma unroll
  for (int mi=0;mi<4;mi++){
    #pragma unroll
    for (int ni=0;ni<4;ni++){
      int col = colBase + wc*64 + ni*16 + lr;
      float bv = bias[col];
      #pragma unroll
      for (int r=0;r<4;r++){
        int row = rowBase + wr*64 + mi*16 + g4*4 + r;
        float v = acc[mi][ni][r] + bv;
        if (epi) v = 1.f/(1.f + expf(-v*KSCALE));
        F[(size_t)row*D_ + col] = bf16r(v);
      }
    }
  }
}

// ---------------- 128x64 MFMA GEMM (fp32 out): output projection ----------------
__global__ __launch_bounds__(256) void gemm1(
  const unsigned short* __restrict__ A, const unsigned short* __restrict__ Bt,
  const float* __restrict__ bias, float* __restrict__ C)
{
  int rowBase = blockIdx.x*128, colBase = blockIdx.y*64;
  __shared__ __align__(16) unsigned short As[128*32];
  __shared__ __align__(16) unsigned short Bs[64*32];
  int tid = threadIdx.x, w = tid>>6, l = tid&63;
  int lr = l&15, g4 = l>>4;
  f32x4 acc[2][4];
  #pragma unroll
  for (int mi=0;mi<2;mi++)
    #pragma unroll
    for (int ni=0;ni<4;ni++)
      acc[mi][ni] = (f32x4){0.f,0.f,0.f,0.f};

  for (int k0 = 0; k0 < D_; k0 += 32) {
    #pragma unroll
    for (int i=0;i<2;i++){
      int F = (w*2+i)*64 + l;
      int r = F>>2, c16 = F&3;
      int sc = c16 ^ ((r>>1)&3);
      const unsigned short* g = A + (size_t)(rowBase+r)*D_ + k0 + sc*8;
      __builtin_amdgcn_global_load_lds(
        (const __attribute__((address_space(1))) void*)g,
        (__attribute__((address_space(3))) void*)(As + (size_t)(w*2+i)*512), 16, 0, 0);
    }
    {
      int F = w*64 + l;
      int r = F>>2, c16 = F&3;
      int sc = c16 ^ ((r>>1)&3);
      const unsigned short* g = Bt + (size_t)(colBase+r)*D_ + k0 + sc*8;
      __builtin_amdgcn_global_load_lds(
        (const __attribute__((address_space(1))) void*)g,
        (__attribute__((address_space(3))) void*)(Bs + (size_t)w*512), 16, 0, 0);
    }
    __syncthreads();
    bf16x8 af[2], bfr[4];
    #pragma unroll
    for (int mi=0;mi<2;mi++){
      int row = w*32 + mi*16 + lr;
      af[mi] = *(const bf16x8*)(As + row*32 + ((g4 ^ ((row>>1)&3))*8));
    }
    #pragma unroll
    for (int ni=0;ni<4;ni++){
      int n = ni*16 + lr;
      bfr[ni] = *(const bf16x8*)(Bs + n*32 + ((g4 ^ ((n>>1)&3))*8));
    }
    #pragma unroll
    for (int mi=0;mi<2;mi++)
      #pragma unroll
      for (int ni=0;ni<4;ni++)
        acc[mi][ni] = __builtin_amdgcn_mfma_f32_16x16x32_bf16(af[mi], bfr[ni], acc[mi][ni], 0,0,0);
    __syncthreads();
  }

  #pragma unroll
  for (int mi=0;mi<2;mi++){
    #pragma unroll
    for (int ni=0;ni<4;ni++){
      int col = colBase + ni*16 + lr;
      float bv = bias[col];
      #pragma unroll
      for (int r=0;r<4;r++){
        int row = rowBase + w*32 + mi*16 + g4*4 + r;
        C[(size_t)row*D_ + col] = acc[mi][ni][r] + bv;
      }
    }
  }
}

// ---------------- per-(b,l,h) scalar gates; GL/RR in [bh][l] layout ----------------
__global__ __launch_bounds__(256) void scalars_kernel(
  const float* __restrict__ X, const unsigned short* __restrict__ Kbf,
  const float* __restrict__ Wg, const float* __restrict__ bg,
  const float* __restrict__ Ws, const float* __restrict__ bs,
  float* __restrict__ GL, float* __restrict__ RR)
{
  int item = blockIdx.x * 4 + (threadIdx.x >> 6);
  int ln = threadIdx.x & 63;
  int row = item >> 4;
  int h = item & 15;
  float xv = X[(size_t)row*D_ + h*64 + ln];
  float kv = bf2f(Kbf[(size_t)row*D_ + h*64 + ln]);
  float gdot = xv * Wg[ln];
  float rdot = kv * Ws[ln];
  #pragma unroll
  for (int off = 32; off; off >>= 1) {
    gdot += __shfl_xor(gdot, off);
    rdot += __shfl_xor(rdot, off);
  }
  if (ln == 0) {
    int b = row >> 10, l = row & 1023;
    size_t o = (size_t)(b*16 + h)*L_ + l;
    float glogit = gdot + bg[0];
    float sg = 1.f/(1.f+expf(-glogit));
    sg = fmaxf(sg, 1e-6f);
    GL[o] = logf(sg);
    float rlogit = rdot + bs[0];
    RR[o] = rlogit / (1.f + expf(-rlogit));
  }
}

// ---------------- AR chunk sum (in-block gate prefix) ----------------
__global__ __launch_bounds__(256) void ar_chunk_sum(
  const unsigned short* __restrict__ Kbf, const unsigned short* __restrict__ Xbf,
  const float* __restrict__ GL, const float* __restrict__ RR,
  float* __restrict__ CS)
{
  int bh = blockIdx.x, c = blockIdx.y;
  int b = bh >> 4, h = bh & 15;
  int row0 = b*L_ + c*CHUNK;
  __shared__ __align__(16) unsigned short kt_t[64*PT];   // K^T [d][j]
  __shared__ __align__(16) unsigned short cv_t[64*PT];   // (cf*V)^T [e][j]
  __shared__ __align__(16) float uni[64*PS];
  __shared__ float cf_s[64];
  int tid = threadIdx.x;
  if (tid < 64) gate_prefix(GL, RR, bh, c, tid, cf_s, nullptr);
  __syncthreads();
  const unsigned short* kg = Kbf + (size_t)row0*D_ + h*64;
  const unsigned short* vg = Xbf + (size_t)row0*D_ + h*64;
  #pragma unroll
  for (int t=0;t<2;t++){
    int j = (tid>>3) + t*32;
    int d0 = (tid&7)*8;
    bf16x8 kv = *(const bf16x8*)&kg[(size_t)j*D_ + d0];
    bf16x8 vv = *(const bf16x8*)&vg[(size_t)j*D_ + d0];
    float cfj = cf_s[j];
    #pragma unroll
    for (int i=0;i<8;i++){
      kt_t[(d0+i)*PT + j] = (unsigned short)kv[i];
      cv_t[(d0+i)*PT + j] = bf16r(bf2f((unsigned short)vv[i]) * cfj);
    }
  }
  __syncthreads();
  int w = tid>>6, l = tid&63, lr = l&15, g4 = l>>4;
  f32x4 acc[4];
  #pragma unroll
  for (int ni=0;ni<4;ni++) acc[ni] = (f32x4){0.f,0.f,0.f,0.f};
  #pragma unroll
  for (int kk=0;kk<2;kk++){
    bf16x8 a = *(const bf16x8*)&cv_t[(w*16+lr)*PT + kk*32 + g4*8];
    #pragma unroll
    for (int ni=0;ni<4;ni++){
      bf16x8 bb = *(const bf16x8*)&kt_t[(ni*16+lr)*PT + kk*32 + g4*8];
      acc[ni] = __builtin_amdgcn_mfma_f32_16x16x32_bf16(a, bb, acc[ni], 0,0,0);
    }
  }
  #pragma unroll
  for (int ni=0;ni<4;ni++)
    #pragma unroll
    for (int r=0;r<4;r++)
      uni[(w*16+g4*4+r)*PS + ni*16+lr] = acc[ni][r];
  __syncthreads();
  float* out = CS + ((size_t)bh*NCH + c)*4096;
  #pragma unroll
  for (int t=0;t<4;t++){
    int idx = tid + t*256;
    int r = idx>>4, s = idx&15;
    *(float4*)&out[r*64 + s*4] = *(float4*)&uni[r*PS + s*4];
  }
}

// ---------------- fused AR O1 + MA chunk sum ----------------
__global__ __launch_bounds__(256) void ar_o1_fused(
  const unsigned short* __restrict__ Qbf, const unsigned short* __restrict__ Kbf,
  const unsigned short* __restrict__ Xbf, const unsigned short* __restrict__ K2bf,
  const float* __restrict__ GL, const float* __restrict__ RR,
  const float* __restrict__ CSA, float* __restrict__ CSM,
  float* __restrict__ O1)
{
  int bh = blockIdx.x, c = blockIdx.y;
  int b = bh >> 4, h = bh & 15;
  int row0 = b*L_ + c*CHUNK;
  __shared__ __align__(16) unsigned short q_t[64*PT];
  __shared__ __align__(16) unsigned short k_t[64*PT];    // K [j][d]; later E^T [e][j]
  __shared__ __align__(16) unsigned short vt_t[64*PT];   // V^T [e][j]; later k2^T [d][j]
  __shared__ __align__(16) unsigned short st_t[64*PT];   // Sc^T carry
  __shared__ __align__(16) float uni[64*PS];             // P stage / O1 stage / CS stage
  unsigned short* p_t = (unsigned short*)uni;
  __shared__ float cf_s[64], gc_s[64];
  int tid = threadIdx.x;
  if (tid < 64) gate_prefix(GL, RR, bh, c, tid, cf_s, gc_s);
  const unsigned short* qg = Qbf + (size_t)row0*D_ + h*64;
  const unsigned short* kg = Kbf + (size_t)row0*D_ + h*64;
  const unsigned short* vg = Xbf + (size_t)row0*D_ + h*64;
  const float* csb = CSA + (size_t)bh*NCH*4096;
  // inline exclusive prefix over raw AR chunk sums
  {
    float carry[16];
    #pragma unroll
    for (int i=0;i<16;i++) carry[i] = 0.f;
    const float* cb = csb + (size_t)tid*16;
    for (int c2=0;c2<c;c2++){
      const float4* p4 = (const float4*)(cb + (size_t)c2*4096);
      float4 a0=p4[0],a1=p4[1],a2=p4[2],a3=p4[3];
      carry[0]+=a0.x; carry[1]+=a0.y; carry[2]+=a0.z; carry[3]+=a0.w;
      carry[4]+=a1.x; carry[5]+=a1.y; carry[6]+=a1.z; carry[7]+=a1.w;
      carry[8]+=a2.x; carry[9]+=a2.y; carry[10]+=a2.z; carry[11]+=a2.w;
      carry[12]+=a3.x; carry[13]+=a3.y; carry[14]+=a3.z; carry[15]+=a3.w;
    }
    unsigned short buf[16];
    #pragma unroll
    for (int i=0;i<16;i++) buf[i] = bf16r(carry[i]);
    int row = tid>>2, col = (tid&3)*16;
    *(uint4*)&st_t[row*PT + col]     = *(uint4*)&buf[0];
    *(uint4*)&st_t[row*PT + col + 8] = *(uint4*)&buf[8];
  }
  #pragma unroll
  for (int t=0;t<2;t++){
    int idx = tid + t*256;
    int j = idx>>3, s = idx&7;
    *(uint4*)&q_t[j*PT + s*8] = *(const uint4*)&qg[(size_t)j*D_ + s*8];
    *(uint4*)&k_t[j*PT + s*8] = *(const uint4*)&kg[(size_t)j*D_ + s*8];
  }
  #pragma unroll
  for (int t=0;t<2;t++){
    int j = (tid>>3) + t*32;
    int e0 = (tid&7)*8;
    bf16x8 vv = *(const bf16x8*)&vg[(size_t)j*D_ + e0];
    #pragma unroll
    for (int i=0;i<8;i++) vt_t[(e0+i)*PT + j] = (unsigned short)vv[i];
  }
  __syncthreads();
  int w = tid>>6, l = tid&63, lr = l&15, g4 = l>>4;
  // mfma1: P = causal(Q @ K^T) * cf
  f32x4 acc[4];
  #pragma unroll
  for (int ni=0;ni<4;ni++) acc[ni] = (f32x4){0.f,0.f,0.f,0.f};
  #pragma unroll
  for (int kk=0;kk<2;kk++){
    bf16x8 a = *(const bf16x8*)&q_t[(w*16+lr)*PT + kk*32 + g4*8];
    #pragma unroll
    for (int ni=0;ni<4;ni++){
      bf16x8 bb = *(const bf16x8*)&k_t[(ni*16+lr)*PT + kk*32 + g4*8];
      acc[ni] = __builtin_amdgcn_mfma_f32_16x16x32_bf16(a, bb, acc[ni], 0,0,0);
    }
  }
  #pragma unroll
  for (int ni=0;ni<4;ni++){
    int j = ni*16 + lr;
    float cf = cf_s[j];
    #pragma unroll
    for (int r=0;r<4;r++){
      int row = w*16 + g4*4 + r;
      float v = (j <= row) ? acc[ni][r]*cf : 0.f;
      p_t[row*PT + j] = bf16r(v);
    }
  }
  __syncthreads();
  // mfma2: O1 = Gc*(P@V + Q@Sc^T)
  #pragma unroll
  for (int ni=0;ni<4;ni++) acc[ni] = (f32x4){0.f,0.f,0.f,0.f};
  #pragma unroll
  for (int kk=0;kk<2;kk++){
    bf16x8 ap = *(const bf16x8*)&p_t[(w*16+lr)*PT + kk*32 + g4*8];
    bf16x8 aq = *(const bf16x8*)&q_t[(w*16+lr)*PT + kk*32 + g4*8];
    #pragma unroll
    for (int ni=0;ni<4;ni++){
      bf16x8 bv = *(const bf16x8*)&vt_t[(ni*16+lr)*PT + kk*32 + g4*8];
      bf16x8 bs = *(const bf16x8*)&st_t[(ni*16+lr)*PT + kk*32 + g4*8];
      acc[ni] = __builtin_amdgcn_mfma_f32_16x16x32_bf16(ap, bv, acc[ni], 0,0,0);
      acc[ni] = __builtin_amdgcn_mfma_f32_16x16x32_bf16(aq, bs, acc[ni], 0,0,0);
    }
  }
  __syncthreads();   // all p_t reads done before uni overwrite
  #pragma unroll
  for (int ni=0;ni<4;ni++)
    #pragma unroll
    for (int r=0;r<4;r++){
      int row = w*16 + g4*4 + r;
      uni[row*PS + ni*16 + lr] = gc_s[row]*acc[ni][r];
    }
  __syncthreads();   // uni = fp32 O1, stable; mfma2's k_t/vt_t reads done
  // O1 global write + MA-tile staging (both only READ uni)
  #pragma unroll
  for (int t=0;t<4;t++){
    int idx = tid + t*256;
    int r = idx>>4, s = idx&15;
    *(float4*)&O1[(size_t)(row0+r)*D_ + h*64 + s*4] = *(float4*)&uni[r*PS + s*4];
  }
  #pragma unroll
  for (int t=0;t<2;t++){
    int j = (tid>>3) + t*32;
    int d0 = (tid&7)*8;
    bf16x8 kv = *(const bf16x8*)&K2bf[(size_t)(row0+j)*D_ + h*64 + d0];
    float ev[8] = {0.f,0.f,0.f,0.f,0.f,0.f,0.f,0.f};
    if (c*CHUNK + j < L_-1){
      bf16x8 xv = *(const bf16x8*)&Xbf[(size_t)(row0+j+1)*D_ + h*64 + d0];
      #pragma unroll
      for (int i=0;i<8;i++) ev[i] = bf2f((unsigned short)xv[i]) - uni[j*PS + d0 + i];
    }
    #pragma unroll
    for (int i=0;i<8;i++){
      vt_t[(d0+i)*PT + j] = (unsigned short)kv[i];   // k2^T [d][j]
      k_t [(d0+i)*PT + j] = bf16r(ev[i]);            // E^T  [e][j]
    }
  }
  __syncthreads();
  // MA chunk sum: CS_T[e][d] = sum_j E[j][e]*k2[j][d]
  f32x4 acc2[4];
  #pragma unroll
  for (int ni=0;ni<4;ni++) acc2[ni] = (f32x4){0.f,0.f,0.f,0.f};
  #pragma unroll
  for (int kk=0;kk<2;kk++){
    bf16x8 a = *(const bf16x8*)&k_t[(w*16+lr)*PT + kk*32 + g4*8];
    #pragma unroll
    for (int ni=0;ni<4;ni++){
      bf16x8 bb = *(const bf16x8*)&vt_t[(ni*16+lr)*PT + kk*32 + g4*8];
      acc2[ni] = __builtin_amdgcn_mfma_f32_16x16x32_bf16(a, bb, acc2[ni], 0,0,0);
    }
  }
  #pragma unroll
  for (int ni=0;ni<4;ni++)
    #pragma unroll
    for (int r=0;r<4;r++)
      uni[(w*16+g4*4+r)*PS + ni*16+lr] = acc2[ni][r];
  __syncthreads();
  float* outm = CSM + ((size_t)bh*NCH + c)*4096;
  #pragma unroll
  for (int t=0;t<4;t++){
    int idx = tid + t*256;
    int r = idx>>4, s = idx&15;
    *(float4*)&outm[r*64 + s*4] = *(float4*)&uni[r*PS + s*4];
  }
}

// ---------------- MA O2 per chunk (inline carry); writes final bf16 O ----------------
__global__ __launch_bounds__(256) void ma_o2_mfma(
  const unsigned short* __restrict__ Qbf, const unsigned short* __restrict__ K2bf,
  const unsigned short* __restrict__ Xbf, const float* __restrict__ CS,
  const float* __restrict__ O1, unsigned short* __restrict__ Obf)
{
  int bh = blockIdx.x, c = blockIdx.y;
  int b = bh >> 4, h = bh & 15;
  int row0 = b*L_ + c*CHUNK;
  __shared__ __align__(16) unsigned short q_t[64*PT];    // q2 [t][d]
  __shared__ __align__(16) unsigned short k_t[64*PT];    // k2 [j][d]
  __shared__ __align__(16) unsigned short et_t[64*PT];   // E^T [e][j]
  __shared__ __align__(16) unsigned short tt_t[64*PT];   // Tc^T carry
  __shared__ __align__(16) float uni[64*PS];
  unsigned short* p_t = (unsigned short*)uni;
  int tid = threadIdx.x;
  const unsigned short* qg = Qbf  + (size_t)row0*D_ + h*64;
  const unsigned short* kg = K2bf + (size_t)row0*D_ + h*64;
  const float* csb = CS + (size_t)bh*NCH*4096;
  {
    float carry[16];
    #pragma unroll
    for (int i=0;i<16;i++) carry[i] = 0.f;
    const float* cb = csb + (size_t)tid*16;
    for (int c2=0;c2<c;c2++){
      const float4* p4 = (const float4*)(cb + (size_t)c2*4096);
      float4 a0=p4[0],a1=p4[1],a2=p4[2],a3=p4[3];
      carry[0]+=a0.x; carry[1]+=a0.y; carry[2]+=a0.z; carry[3]+=a0.w;
      carry[4]+=a1.x; carry[5]+=a1.y; carry[6]+=a1.z; carry[7]+=a1.w;
      carry[8]+=a2.x; carry[9]+=a2.y; carry[10]+=a2.z; carry[11]+=a2.w;
      carry[12]+=a3.x; carry[13]+=a3.y; carry[14]+=a3.z; carry[15]+=a3.w;
    }
    unsigned short buf[16];
    #pragma unroll
    for (int i=0;i<16;i++) buf[i] = bf16r(carry[i]);
    int row = tid>>2, col = (tid&3)*16;
    *(uint4*)&tt_t[row*PT + col]     = *(uint4*)&buf[0];
    *(uint4*)&tt_t[row*PT + col + 8] = *(uint4*)&buf[8];
  }
  #pragma unroll
  for (int t=0;t<2;t++){
    int idx = tid + t*256;
    int j = idx>>3, s = idx&7;
    *(uint4*)&k_t[j*PT + s*8] = *(const uint4*)&kg[(size_t)j*D_ + s*8];
  }
  #pragma unroll
  for (int t=0;t<2;t++){
    int j = (tid>>3) + t*32;
    int d0 = (tid&7)*8;
    bf16x8 qv = *(const bf16x8*)&qg[(size_t)j*D_ + d0];
    unsigned short qb[8];
    #pragma unroll
    for (int i=0;i<8;i++){
      float q = bf2f((unsigned short)qv[i]);
      qb[i] = bf16r((q > 0.f ? 0.02f*q : q) * 0.125f);
    }
    *(uint4*)&q_t[j*PT + d0] = *(uint4*)&qb[0];
    float ev[8] = {0.f,0.f,0.f,0.f,0.f,0.f,0.f,0.f};
    if (c*CHUNK + j < L_-1){
      bf16x8 xv = *(const bf16x8*)&Xbf[(size_t)(row0+j+1)*D_ + h*64 + d0];
      const float4* op = (const float4*)&O1[(size_t)(row0+j)*D_ + h*64 + d0];
      float4 o0 = op[0], o1v = op[1];
      ev[0]=bf2f((unsigned short)xv[0])-o0.x;  ev[1]=bf2f((unsigned short)xv[1])-o0.y;
      ev[2]=bf2f((unsigned short)xv[2])-o0.z;  ev[3]=bf2f((unsigned short)xv[3])-o0.w;
      ev[4]=bf2f((unsigned short)xv[4])-o1v.x; ev[5]=bf2f((unsigned short)xv[5])-o1v.y;
      ev[6]=bf2f((unsigned short)xv[6])-o1v.z; ev[7]=bf2f((unsigned short)xv[7])-o1v.w;
    }
    #pragma unroll
    for (int i=0;i<8;i++) et_t[(d0+i)*PT + j] = bf16r(ev[i]);
  }
  __syncthreads();
  int w = tid>>6, l = tid&63, lr = l&15, g4 = l>>4;
  f32x4 acc[4];
  #pragma unroll
  for (int ni=0;ni<4;ni++) acc[ni] = (f32x4){0.f,0.f,0.f,0.f};
  #pragma unroll
  for (int kk=0;kk<2;kk++){
    bf16x8 a = *(const bf16x8*)&q_t[(w*16+lr)*PT + kk*32 + g4*8];
    #pragma unroll
    for (int ni=0;ni<4;ni++){
      bf16x8 bb = *(const bf16x8*)&k_t[(ni*16+lr)*PT + kk*32 + g4*8];
      acc[ni] = __builtin_amdgcn_mfma_f32_16x16x32_bf16(a, bb, acc[ni], 0,0,0);
    }
  }
  #pragma unroll
  for (int ni=0;ni<4;ni++){
    int j = ni*16 + lr;
    #pragma unroll
    for (int r=0;r<4;r++){
      int row = w*16 + g4*4 + r;
      float v = (j <= row) ? acc[ni][r] : 0.f;
      p_t[row*PT + j] = bf16r(v);
    }
  }
  __syncthreads();
  #pragma unroll
  for (int ni=0;ni<4;ni++) acc[ni] = (f32x4){0.f,0.f,0.f,0.f};
  #pragma unroll
  for (int kk=0;kk<2;kk++){
    bf16x8 ap = *(const bf16x8*)&p_t[(w*16+lr)*PT + kk*32 + g4*8];
    bf16x8 aq = *(const bf16x8*)&q_t[(w*16+lr)*PT + kk*32 + g4*8];
    #pragma unroll
    for (int ni=0;ni<4;ni++){
      bf16x8 be = *(const bf16x8*)&et_t[(ni*16+lr)*PT + kk*32 + g4*8];
      bf16x8 bt = *(const bf16x8*)&tt_t[(ni*16+lr)*PT + kk*32 + g4*8];
      acc[ni] = __builtin_amdgcn_mfma_f32_16x16x32_bf16(ap, be, acc[ni], 0,0,0);
      acc[ni] = __builtin_amdgcn_mfma_f32_16x16x32_bf16(aq, bt, acc[ni], 0,0,0);
    }
  }
  __syncthreads();
  #pragma unroll
  for (int ni=0;ni<4;ni++)
    #pragma unroll
    for (int r=0;r<4;r++){
      int row = w*16 + g4*4 + r;
      uni[row*PS + ni*16 + lr] = acc[ni][r];
    }
  __syncthreads();
  #pragma unroll
  for (int t=0;t<4;t++){
    int idx = tid + t*256;
    int r = idx>>4, s = idx&15;
    if (c*CHUNK + r < L_-1) {
      const float4 gv = *(const float4*)&O1[(size_t)(row0+r+1)*D_ + h*64 + s*4];
      float4 uv = *(float4*)&uni[r*PS + s*4];
      ushort4 o;
      o.x = bf16r(gv.x+uv.x); o.y = bf16r(gv.y+uv.y);
      o.z = bf16r(gv.z+uv.z); o.w = bf16r(gv.w+uv.w);
      *(ushort4*)&Obf[(size_t)(row0+r+1)*D_ + h*64 + s*4] = o;
    }
  }
  if (c == 0 && tid < 16) {
    const float4 gv = *(const float4*)&O1[(size_t)row0*D_ + h*64 + tid*4];
    ushort4 o;
    o.x = bf16r(gv.x); o.y = bf16r(gv.y); o.z = bf16r(gv.z); o.w = bf16r(gv.w);
    *(ushort4*)&Obf[(size_t)row0*D_ + h*64 + tid*4] = o;
  }
}

extern "C" void kernel_launch(void* const* d_in, const int* in_sizes, int n_in,
                              void* d_out, int out_size, void* d_ws, size_t ws_size,
                              hipStream_t stream) {
  const float* x  = (const float*)d_in[0];
  const float* Wq = (const float*)d_in[1];
  const float* bq = (const float*)d_in[2];
  const float* Wk1= (const float*)d_in[3];
  const float* bk1= (const float*)d_in[4];
  const float* Wk2= (const float*)d_in[5];
  const float* bk2= (const float*)d_in[6];
  const float* Wg = (const float*)d_in[7];
  const float* bg = (const float*)d_in[8];
  const float* Ws = (const float*)d_in[9];
  const float* bs = (const float*)d_in[10];
  const float* Wp = (const float*)d_in[11];
  const float* bp = (const float*)d_in[12];
  float* out = (float*)d_out;

  float* ws = (float*)d_ws;
  size_t MD = (size_t)M_*D_;
  float* O1b = ws;
  float* CSA = O1b + MD;                     // AR chunk sums
  float* CSM = CSA + (size_t)32*NCH*4096;    // MA chunk sums
  float* GLb = CSM + (size_t)32*NCH*4096;    // [bh][l]
  float* RRb = GLb + (size_t)32*L_;
  unsigned short* Xbf   = (unsigned short*)(RRb + (size_t)32*L_);
  unsigned short* Qbfs  = Xbf  + MD;
  unsigned short* Kbfs  = Qbfs + MD;
  unsigned short* K2bfs = Kbfs + MD;
  unsigned short* Obf   = K2bfs+ MD;
  unsigned short* Wt0   = Obf + MD;
  unsigned short* Wt1   = Wt0 + (size_t)D_*D_;
  unsigned short* Wt2   = Wt1 + (size_t)D_*D_;
  unsigned short* Wt3   = Wt2 + (size_t)D_*D_;

  dim3 gcv(32, 16, 5);
  convert_all<<<gcv, 256, 0, stream>>>(x, Wq, Wk1, Wk2, Wp, Xbf, Wt0, Wt1, Wt2, Wt3);

  dim3 gg(M_/128, D_/128, 3);
  gemm3<<<gg, 256, 0, stream>>>(Xbf, Wt0, Wt1, Wt2, bq, bk1, bk2, Qbfs, Kbfs, K2bfs);

  scalars_kernel<<<(M_*H_)/4, 256, 0, stream>>>(x, Kbfs, Wg, bg, Ws, bs, GLb, RRb);

  dim3 gc(32, NCH);
  ar_chunk_sum<<<gc, 256, 0, stream>>>(Kbfs, Xbf, GLb, RRb, CSA);
  ar_o1_fused<<<gc, 256, 0, stream>>>(Qbfs, Kbfs, Xbf, K2bfs, GLb, RRb, CSA, CSM, O1b);
  ma_o2_mfma<<<gc, 256, 0, stream>>>(Qbfs, K2bfs, Xbf, CSM, O1b, Obf);

  dim3 go(M_/128, D_/64);
  gemm1<<<go, 256, 0, stream>>>(Obf, Wt3, bp, out);
}

// Round 10
// 180.166 us; speedup vs baseline: 1.0281x; 1.0281x over previous
//
#include <hip/hip_runtime.h>
#include <hip/hip_bf16.h>
#include <math.h>

#define B_  2
#define L_  1024
#define D_  1024
#define H_  16
#define DH_ 64
#define M_  (B_*L_)   // 2048
#define CHUNK 64
#define NCH (L_/CHUNK)   // 16
#define PT 72   // bf16 LDS tile pad (shorts): rows 144B, 16B-aligned
#define PS 68   // f32 LDS out-stage pad (floats): rows 272B, 16B-aligned

#define KSCALE (0.02f/32.0f)   // /sqrt(D) * 0.02

using bf16x8 = __attribute__((ext_vector_type(8))) short;
using f32x4  = __attribute__((ext_vector_type(4))) float;

__device__ __forceinline__ unsigned short bf16r(float f){
  union{float f; unsigned int u;} x; x.f = f;
  unsigned int r = x.u + 0x7FFF + ((x.u>>16)&1);
  return (unsigned short)(r>>16);
}
__device__ __forceinline__ float bf2f(unsigned short u){
  union{unsigned int u; float f;} x; x.u = ((unsigned int)u)<<16; return x.f;
}

// in-wave gate prefix for chunk c of bh. lanes 0..63.
// carry = sum GL[0..c*64) via strided INDEPENDENT per-lane loads + one reduce.
__device__ __forceinline__ void gate_prefix(
  const float* __restrict__ GL, const float* __restrict__ RR,
  int bh, int c, int l, float* cf_s, float* gc_s)
{
  const float* g = GL + (size_t)bh*L_;
  float part = 0.f;
  for (int i = l; i < c*64; i += 64) part += g[i];
  #pragma unroll
  for (int off = 32; off; off >>= 1) part += __shfl_xor(part, off);
  float x = g[c*64 + l];
  #pragma unroll
  for (int off = 1; off < 64; off <<= 1){
    float t = __shfl_up(x, off);
    if (l >= off) x += t;
  }
  float cum = part + x;
  float lc = fminf(fmaxf(cum, -30.f), 30.f);
  float gc = expf(lc) + 1e-6f;
  cf_s[l] = RR[(size_t)bh*L_ + c*64 + l] / gc;
  if (gc_s) gc_s[l] = gc;
}

// chunk-carry (exclusive prefix) into registers: 16 consecutive floats/thread
__device__ __forceinline__ void chunk_carry(
  const float* __restrict__ csb, int c, int tid, float* carry)
{
  #pragma unroll
  for (int i=0;i<16;i++) carry[i] = 0.f;
  const float4* cb = (const float4*)(csb + (size_t)tid*16);
  #pragma unroll 2
  for (int c2=0;c2<c;c2++){
    const float4* p4 = cb + (size_t)c2*1024;
    float4 a0=p4[0],a1=p4[1],a2=p4[2],a3=p4[3];
    carry[0]+=a0.x; carry[1]+=a0.y; carry[2]+=a0.z; carry[3]+=a0.w;
    carry[4]+=a1.x; carry[5]+=a1.y; carry[6]+=a1.z; carry[7]+=a1.w;
    carry[8]+=a2.x; carry[9]+=a2.y; carry[10]+=a2.z; carry[11]+=a2.w;
    carry[12]+=a3.x; carry[13]+=a3.y; carry[14]+=a3.z; carry[15]+=a3.w;
  }
}

// ---------------- all conversions in one launch ----------------
__global__ __launch_bounds__(256) void convert_all(
  const float* __restrict__ X,
  const float* __restrict__ W0, const float* __restrict__ W1,
  const float* __restrict__ W2, const float* __restrict__ W3,
  unsigned short* __restrict__ Xbf,
  unsigned short* __restrict__ T0, unsigned short* __restrict__ T1,
  unsigned short* __restrict__ T2, unsigned short* __restrict__ T3)
{
  int z = blockIdx.z;
  if (z == 4) {
    int row = blockIdx.x*64 + (threadIdx.x>>2);
    int col = blockIdx.y*64 + (threadIdx.x&3)*16;
    const float4* src = (const float4*)&X[(size_t)row*D_ + col];
    float4 a=src[0], b=src[1], c=src[2], d=src[3];
    unsigned short buf[16] = {
      bf16r(a.x),bf16r(a.y),bf16r(a.z),bf16r(a.w),
      bf16r(b.x),bf16r(b.y),bf16r(b.z),bf16r(b.w),
      bf16r(c.x),bf16r(c.y),bf16r(c.z),bf16r(c.w),
      bf16r(d.x),bf16r(d.y),bf16r(d.z),bf16r(d.w)};
    *(uint4*)&Xbf[(size_t)row*D_ + col]     = *(uint4*)&buf[0];
    *(uint4*)&Xbf[(size_t)row*D_ + col + 8] = *(uint4*)&buf[8];
    return;
  }
  if (blockIdx.x >= 16) return;
  const float* W = z==0?W0: z==1?W1: z==2?W2: W3;
  unsigned short* T = z==0?T0: z==1?T1: z==2?T2: T3;
  __shared__ float tile[64][65];
  int kBase = blockIdx.x*64, nBase = blockIdx.y*64;
  #pragma unroll
  for (int i=0;i<16;i++){
    int idx = threadIdx.x + i*256;
    int r = idx>>6, c = idx&63;
    tile[r][c] = W[(size_t)(kBase+r)*D_ + nBase+c];
  }
  __syncthreads();
  #pragma unroll
  for (int i=0;i<16;i++){
    int idx = threadIdx.x + i*256;
    int n = idx>>6, k = idx&63;
    T[(size_t)(nBase+n)*D_ + kBase+k] = bf16r(tile[k][n]);
  }
}

// ---------------- 128x128 MFMA GEMM (bf16 out): 3 projections ----------------
__global__ __launch_bounds__(256) void gemm3(
  const unsigned short* __restrict__ A,
  const unsigned short* __restrict__ T0, const unsigned short* __restrict__ T1,
  const unsigned short* __restrict__ T2,
  const float* __restrict__ b0, const float* __restrict__ b1, const float* __restrict__ b2,
  unsigned short* __restrict__ F0, unsigned short* __restrict__ F1,
  unsigned short* __restrict__ F2)
{
  int z = blockIdx.z;
  const unsigned short* Bt = z==0?T0: z==1?T1: T2;
  const float* bias = z==0?b0: z==1?b1: b2;
  unsigned short* F = z==0?F0: z==1?F1: F2;
  int epi = (z==2) ? 1 : 0;
  int rowBase = blockIdx.x*128, colBase = blockIdx.y*128;

  __shared__ __align__(16) unsigned short As[128*32];
  __shared__ __align__(16) unsigned short Bs[128*32];
  int tid = threadIdx.x, w = tid>>6, l = tid&63;
  int lr = l&15, g4 = l>>4;
  int wr = w>>1, wc = w&1;
  f32x4 acc[4][4];
  #pragma unroll
  for (int mi=0;mi<4;mi++)
    #pragma unroll
    for (int ni=0;ni<4;ni++)
      acc[mi][ni] = (f32x4){0.f,0.f,0.f,0.f};

  for (int k0 = 0; k0 < D_; k0 += 32) {
    #pragma unroll
    for (int i=0;i<2;i++){
      int Fi = (w*2+i)*64 + l;
      int r = Fi>>2, c16 = Fi&3;
      int sc = c16 ^ ((r>>1)&3);
      const unsigned short* ga = A  + (size_t)(rowBase+r)*D_ + k0 + sc*8;
      const unsigned short* gb = Bt + (size_t)(colBase+r)*D_ + k0 + sc*8;
      __builtin_amdgcn_global_load_lds(
        (const __attribute__((address_space(1))) void*)ga,
        (__attribute__((address_space(3))) void*)(As + (size_t)(w*2+i)*512), 16, 0, 0);
      __builtin_amdgcn_global_load_lds(
        (const __attribute__((address_space(1))) void*)gb,
        (__attribute__((address_space(3))) void*)(Bs + (size_t)(w*2+i)*512), 16, 0, 0);
    }
    __syncthreads();
    bf16x8 af[4], bfr[4];
    #pragma unroll
    for (int mi=0;mi<4;mi++){
      int row = wr*64 + mi*16 + lr;
      af[mi] = *(const bf16x8*)(As + row*32 + ((g4 ^ ((row>>1)&3))*8));
    }
    #pragma unroll
    for (int ni=0;ni<4;ni++){
      int n = wc*64 + ni*16 + lr;
      bfr[ni] = *(const bf16x8*)(Bs + n*32 + ((g4 ^ ((n>>1)&3))*8));
    }
    #pragma unroll
    for (int mi=0;mi<4;mi++)
      #pragma unroll
      for (int ni=0;ni<4;ni++)
        acc[mi][ni] = __builtin_amdgcn_mfma_f32_16x16x32_bf16(af[mi], bfr[ni], acc[mi][ni], 0,0,0);
    __syncthreads();
  }

  #pragma unroll
  for (int mi=0;mi<4;mi++){
    #pragma unroll
    for (int ni=0;ni<4;ni++){
      int col = colBase + wc*64 + ni*16 + lr;
      float bv = bias[col];
      #pragma unroll
      for (int r=0;r<4;r++){
        int row = rowBase + wr*64 + mi*16 + g4*4 + r;
        float v = acc[mi][ni][r] + bv;
        if (epi) v = 1.f/(1.f + expf(-v*KSCALE));
        F[(size_t)row*D_ + col] = bf16r(v);
      }
    }
  }
}

// ---------------- 128x64 MFMA GEMM (fp32 out): output projection ----------------
__global__ __launch_bounds__(256) void gemm1(
  const unsigned short* __restrict__ A, const unsigned short* __restrict__ Bt,
  const float* __restrict__ bias, float* __restrict__ C)
{
  int rowBase = blockIdx.x*128, colBase = blockIdx.y*64;
  __shared__ __align__(16) unsigned short As[128*32];
  __shared__ __align__(16) unsigned short Bs[64*32];
  int tid = threadIdx.x, w = tid>>6, l = tid&63;
  int lr = l&15, g4 = l>>4;
  f32x4 acc[2][4];
  #pragma unroll
  for (int mi=0;mi<2;mi++)
    #pragma unroll
    for (int ni=0;ni<4;ni++)
      acc[mi][ni] = (f32x4){0.f,0.f,0.f,0.f};

  for (int k0 = 0; k0 < D_; k0 += 32) {
    #pragma unroll
    for (int i=0;i<2;i++){
      int F = (w*2+i)*64 + l;
      int r = F>>2, c16 = F&3;
      int sc = c16 ^ ((r>>1)&3);
      const unsigned short* g = A + (size_t)(rowBase+r)*D_ + k0 + sc*8;
      __builtin_amdgcn_global_load_lds(
        (const __attribute__((address_space(1))) void*)g,
        (__attribute__((address_space(3))) void*)(As + (size_t)(w*2+i)*512), 16, 0, 0);
    }
    {
      int F = w*64 + l;
      int r = F>>2, c16 = F&3;
      int sc = c16 ^ ((r>>1)&3);
      const unsigned short* g = Bt + (size_t)(colBase+r)*D_ + k0 + sc*8;
      __builtin_amdgcn_global_load_lds(
        (const __attribute__((address_space(1))) void*)g,
        (__attribute__((address_space(3))) void*)(Bs + (size_t)w*512), 16, 0, 0);
    }
    __syncthreads();
    bf16x8 af[2], bfr[4];
    #pragma unroll
    for (int mi=0;mi<2;mi++){
      int row = w*32 + mi*16 + lr;
      af[mi] = *(const bf16x8*)(As + row*32 + ((g4 ^ ((row>>1)&3))*8));
    }
    #pragma unroll
    for (int ni=0;ni<4;ni++){
      int n = ni*16 + lr;
      bfr[ni] = *(const bf16x8*)(Bs + n*32 + ((g4 ^ ((n>>1)&3))*8));
    }
    #pragma unroll
    for (int mi=0;mi<2;mi++)
      #pragma unroll
      for (int ni=0;ni<4;ni++)
        acc[mi][ni] = __builtin_amdgcn_mfma_f32_16x16x32_bf16(af[mi], bfr[ni], acc[mi][ni], 0,0,0);
    __syncthreads();
  }

  #pragma unroll
  for (int mi=0;mi<2;mi++){
    #pragma unroll
    for (int ni=0;ni<4;ni++){
      int col = colBase + ni*16 + lr;
      float bv = bias[col];
      #pragma unroll
      for (int r=0;r<4;r++){
        int row = rowBase + w*32 + mi*16 + g4*4 + r;
        C[(size_t)row*D_ + col] = acc[mi][ni][r] + bv;
      }
    }
  }
}

// ---------------- per-(b,l,h) scalar gates; GL/RR in [bh][l] layout ----------------
__global__ __launch_bounds__(256) void scalars_kernel(
  const float* __restrict__ X, const unsigned short* __restrict__ Kbf,
  const float* __restrict__ Wg, const float* __restrict__ bg,
  const float* __restrict__ Ws, const float* __restrict__ bs,
  float* __restrict__ GL, float* __restrict__ RR)
{
  int item = blockIdx.x * 4 + (threadIdx.x >> 6);
  int ln = threadIdx.x & 63;
  int row = item >> 4;
  int h = item & 15;
  float xv = X[(size_t)row*D_ + h*64 + ln];
  float kv = bf2f(Kbf[(size_t)row*D_ + h*64 + ln]);
  float gdot = xv * Wg[ln];
  float rdot = kv * Ws[ln];
  #pragma unroll
  for (int off = 32; off; off >>= 1) {
    gdot += __shfl_xor(gdot, off);
    rdot += __shfl_xor(rdot, off);
  }
  if (ln == 0) {
    int b = row >> 10, l = row & 1023;
    size_t o = (size_t)(b*16 + h)*L_ + l;
    float glogit = gdot + bg[0];
    float sg = 1.f/(1.f+expf(-glogit));
    sg = fmaxf(sg, 1e-6f);
    GL[o] = logf(sg);
    float rlogit = rdot + bs[0];
    RR[o] = rlogit / (1.f + expf(-rlogit));
  }
}

// ---------------- AR chunk sum (in-block gate prefix) ----------------
__global__ __launch_bounds__(256) void ar_chunk_sum(
  const unsigned short* __restrict__ Kbf, const unsigned short* __restrict__ Xbf,
  const float* __restrict__ GL, const float* __restrict__ RR,
  float* __restrict__ CS)
{
  int bh = blockIdx.x, c = blockIdx.y;
  int b = bh >> 4, h = bh & 15;
  int row0 = b*L_ + c*CHUNK;
  __shared__ __align__(16) unsigned short kt_t[64*PT];   // K^T [d][j]
  __shared__ __align__(16) unsigned short cv_t[64*PT];   // (cf*V)^T [e][j]
  __shared__ __align__(16) float uni[64*PS];
  __shared__ float cf_s[64];
  int tid = threadIdx.x;
  if (tid < 64) gate_prefix(GL, RR, bh, c, tid, cf_s, nullptr);
  __syncthreads();
  const unsigned short* kg = Kbf + (size_t)row0*D_ + h*64;
  const unsigned short* vg = Xbf + (size_t)row0*D_ + h*64;
  #pragma unroll
  for (int t=0;t<2;t++){
    int j = (tid>>3) + t*32;
    int d0 = (tid&7)*8;
    bf16x8 kv = *(const bf16x8*)&kg[(size_t)j*D_ + d0];
    bf16x8 vv = *(const bf16x8*)&vg[(size_t)j*D_ + d0];
    float cfj = cf_s[j];
    #pragma unroll
    for (int i=0;i<8;i++){
      kt_t[(d0+i)*PT + j] = (unsigned short)kv[i];
      cv_t[(d0+i)*PT + j] = bf16r(bf2f((unsigned short)vv[i]) * cfj);
    }
  }
  __syncthreads();
  int w = tid>>6, l = tid&63, lr = l&15, g4 = l>>4;
  f32x4 acc[4];
  #pragma unroll
  for (int ni=0;ni<4;ni++) acc[ni] = (f32x4){0.f,0.f,0.f,0.f};
  #pragma unroll
  for (int kk=0;kk<2;kk++){
    bf16x8 a = *(const bf16x8*)&cv_t[(w*16+lr)*PT + kk*32 + g4*8];
    #pragma unroll
    for (int ni=0;ni<4;ni++){
      bf16x8 bb = *(const bf16x8*)&kt_t[(ni*16+lr)*PT + kk*32 + g4*8];
      acc[ni] = __builtin_amdgcn_mfma_f32_16x16x32_bf16(a, bb, acc[ni], 0,0,0);
    }
  }
  #pragma unroll
  for (int ni=0;ni<4;ni++)
    #pragma unroll
    for (int r=0;r<4;r++)
      uni[(w*16+g4*4+r)*PS + ni*16+lr] = acc[ni][r];
  __syncthreads();
  float* out = CS + ((size_t)bh*NCH + c)*4096;
  #pragma unroll
  for (int t=0;t<4;t++){
    int idx = tid + t*256;
    int r = idx>>4, s = idx&15;
    *(float4*)&out[r*64 + s*4] = *(float4*)&uni[r*PS + s*4];
  }
}

// ---------------- fused AR O1 + MA chunk sum (carry staged into k_t after mfma1) ----------------
__global__ __launch_bounds__(256) void ar_o1_fused(
  const unsigned short* __restrict__ Qbf, const unsigned short* __restrict__ Kbf,
  const unsigned short* __restrict__ Xbf, const unsigned short* __restrict__ K2bf,
  const float* __restrict__ GL, const float* __restrict__ RR,
  const float* __restrict__ CSA, float* __restrict__ CSM,
  float* __restrict__ O1)
{
  int bh = blockIdx.x, c = blockIdx.y;
  int b = bh >> 4, h = bh & 15;
  int row0 = b*L_ + c*CHUNK;
  __shared__ __align__(16) unsigned short q_t[64*PT];    // Q [j][d]
  __shared__ __align__(16) unsigned short k_t[64*PT];    // K [j][d] -> Sc^T carry -> E^T
  __shared__ __align__(16) unsigned short vt_t[64*PT];   // V^T [e][j] -> k2^T [d][j]
  __shared__ __align__(16) float uni[64*PS];             // P / O1 / CS stage
  unsigned short* p_t = (unsigned short*)uni;
  __shared__ float cf_s[64], gc_s[64];
  int tid = threadIdx.x;
  if (tid < 64) gate_prefix(GL, RR, bh, c, tid, cf_s, gc_s);
  const unsigned short* qg = Qbf + (size_t)row0*D_ + h*64;
  const unsigned short* kg = Kbf + (size_t)row0*D_ + h*64;
  const unsigned short* vg = Xbf + (size_t)row0*D_ + h*64;
  // carry to registers (overlaps with staging)
  float carry[16];
  chunk_carry(CSA + (size_t)bh*NCH*4096, c, tid, carry);
  #pragma unroll
  for (int t=0;t<2;t++){
    int idx = tid + t*256;
    int j = idx>>3, s = idx&7;
    *(uint4*)&q_t[j*PT + s*8] = *(const uint4*)&qg[(size_t)j*D_ + s*8];
    *(uint4*)&k_t[j*PT + s*8] = *(const uint4*)&kg[(size_t)j*D_ + s*8];
  }
  #pragma unroll
  for (int t=0;t<2;t++){
    int j = (tid>>3) + t*32;
    int e0 = (tid&7)*8;
    bf16x8 vv = *(const bf16x8*)&vg[(size_t)j*D_ + e0];
    #pragma unroll
    for (int i=0;i<8;i++) vt_t[(e0+i)*PT + j] = (unsigned short)vv[i];
  }
  __syncthreads();                                   // B1
  int w = tid>>6, l = tid&63, lr = l&15, g4 = l>>4;
  // mfma1: P = causal(Q @ K^T) * cf
  f32x4 acc[4];
  #pragma unroll
  for (int ni=0;ni<4;ni++) acc[ni] = (f32x4){0.f,0.f,0.f,0.f};
  #pragma unroll
  for (int kk=0;kk<2;kk++){
    bf16x8 a = *(const bf16x8*)&q_t[(w*16+lr)*PT + kk*32 + g4*8];
    #pragma unroll
    for (int ni=0;ni<4;ni++){
      bf16x8 bb = *(const bf16x8*)&k_t[(ni*16+lr)*PT + kk*32 + g4*8];
      acc[ni] = __builtin_amdgcn_mfma_f32_16x16x32_bf16(a, bb, acc[ni], 0,0,0);
    }
  }
  #pragma unroll
  for (int ni=0;ni<4;ni++){
    int j = ni*16 + lr;
    float cf = cf_s[j];
    #pragma unroll
    for (int r=0;r<4;r++){
      int row = w*16 + g4*4 + r;
      float v = (j <= row) ? acc[ni][r]*cf : 0.f;
      p_t[row*PT + j] = bf16r(v);
    }
  }
  __syncthreads();                                   // B2: mfma1 K-reads done
  // stage carry (registers) into k_t space as Sc^T [e][d]
  {
    unsigned short buf[16];
    #pragma unroll
    for (int i=0;i<16;i++) buf[i] = bf16r(carry[i]);
    int row = tid>>2, col = (tid&3)*16;
    *(uint4*)&k_t[row*PT + col]     = *(uint4*)&buf[0];
    *(uint4*)&k_t[row*PT + col + 8] = *(uint4*)&buf[8];
  }
  __syncthreads();                                   // B3
  // mfma2: O1 = Gc*(P@V + Q@Sc^T)
  #pragma unroll
  for (int ni=0;ni<4;ni++) acc[ni] = (f32x4){0.f,0.f,0.f,0.f};
  #pragma unroll
  for (int kk=0;kk<2;kk++){
    bf16x8 ap = *(const bf16x8*)&p_t[(w*16+lr)*PT + kk*32 + g4*8];
    bf16x8 aq = *(const bf16x8*)&q_t[(w*16+lr)*PT + kk*32 + g4*8];
    #pragma unroll
    for (int ni=0;ni<4;ni++){
      bf16x8 bv = *(const bf16x8*)&vt_t[(ni*16+lr)*PT + kk*32 + g4*8];
      bf16x8 bs = *(const bf16x8*)&k_t[(ni*16+lr)*PT + kk*32 + g4*8];
      acc[ni] = __builtin_amdgcn_mfma_f32_16x16x32_bf16(ap, bv, acc[ni], 0,0,0);
      acc[ni] = __builtin_amdgcn_mfma_f32_16x16x32_bf16(aq, bs, acc[ni], 0,0,0);
    }
  }
  __syncthreads();                                   // B4: p_t reads done
  #pragma unroll
  for (int ni=0;ni<4;ni++)
    #pragma unroll
    for (int r=0;r<4;r++){
      int row = w*16 + g4*4 + r;
      uni[row*PS + ni*16 + lr] = gc_s[row]*acc[ni][r];
    }
  __syncthreads();                                   // B5: uni = fp32 O1
  // O1 global write + MA-tile staging (both only READ uni)
  #pragma unroll
  for (int t=0;t<4;t++){
    int idx = tid + t*256;
    int r = idx>>4, s = idx&15;
    *(float4*)&O1[(size_t)(row0+r)*D_ + h*64 + s*4] = *(float4*)&uni[r*PS + s*4];
  }
  #pragma unroll
  for (int t=0;t<2;t++){
    int j = (tid>>3) + t*32;
    int d0 = (tid&7)*8;
    bf16x8 kv = *(const bf16x8*)&K2bf[(size_t)(row0+j)*D_ + h*64 + d0];
    float ev[8] = {0.f,0.f,0.f,0.f,0.f,0.f,0.f,0.f};
    if (c*CHUNK + j < L_-1){
      bf16x8 xv = *(const bf16x8*)&Xbf[(size_t)(row0+j+1)*D_ + h*64 + d0];
      #pragma unroll
      for (int i=0;i<8;i++) ev[i] = bf2f((unsigned short)xv[i]) - uni[j*PS + d0 + i];
    }
    #pragma unroll
    for (int i=0;i<8;i++){
      vt_t[(d0+i)*PT + j] = (unsigned short)kv[i];   // k2^T [d][j]
      k_t [(d0+i)*PT + j] = bf16r(ev[i]);            // E^T  [e][j]
    }
  }
  __syncthreads();                                   // B6
  // MA chunk sum: CS_T[e][d] = sum_j E[j][e]*k2[j][d]
  f32x4 acc2[4];
  #pragma unroll
  for (int ni=0;ni<4;ni++) acc2[ni] = (f32x4){0.f,0.f,0.f,0.f};
  #pragma unroll
  for (int kk=0;kk<2;kk++){
    bf16x8 a = *(const bf16x8*)&k_t[(w*16+lr)*PT + kk*32 + g4*8];
    #pragma unroll
    for (int ni=0;ni<4;ni++){
      bf16x8 bb = *(const bf16x8*)&vt_t[(ni*16+lr)*PT + kk*32 + g4*8];
      acc2[ni] = __builtin_amdgcn_mfma_f32_16x16x32_bf16(a, bb, acc2[ni], 0,0,0);
    }
  }
  __syncthreads();                                   // B7: uni reads (E) done
  #pragma unroll
  for (int ni=0;ni<4;ni++)
    #pragma unroll
    for (int r=0;r<4;r++)
      uni[(w*16+g4*4+r)*PS + ni*16+lr] = acc2[ni][r];
  __syncthreads();                                   // B8
  float* outm = CSM + ((size_t)bh*NCH + c)*4096;
  #pragma unroll
  for (int t=0;t<4;t++){
    int idx = tid + t*256;
    int r = idx>>4, s = idx&15;
    *(float4*)&outm[r*64 + s*4] = *(float4*)&uni[r*PS + s*4];
  }
}

// ---------------- MA O2 per chunk (carry staged into k_t after mfma1); writes final bf16 O ----------------
__global__ __launch_bounds__(256) void ma_o2_mfma(
  const unsigned short* __restrict__ Qbf, const unsigned short* __restrict__ K2bf,
  const unsigned short* __restrict__ Xbf, const float* __restrict__ CS,
  const float* __restrict__ O1, unsigned short* __restrict__ Obf)
{
  int bh = blockIdx.x, c = blockIdx.y;
  int b = bh >> 4, h = bh & 15;
  int row0 = b*L_ + c*CHUNK;
  __shared__ __align__(16) unsigned short q_t[64*PT];    // q2 [t][d]
  __shared__ __align__(16) unsigned short k_t[64*PT];    // k2 [j][d] -> Tc^T carry
  __shared__ __align__(16) unsigned short et_t[64*PT];   // E^T [e][j]
  __shared__ __align__(16) float uni[64*PS];
  unsigned short* p_t = (unsigned short*)uni;
  int tid = threadIdx.x;
  const unsigned short* qg = Qbf  + (size_t)row0*D_ + h*64;
  const unsigned short* kg = K2bf + (size_t)row0*D_ + h*64;
  float carry[16];
  chunk_carry(CS + (size_t)bh*NCH*4096, c, tid, carry);
  #pragma unroll
  for (int t=0;t<2;t++){
    int idx = tid + t*256;
    int j = idx>>3, s = idx&7;
    *(uint4*)&k_t[j*PT + s*8] = *(const uint4*)&kg[(size_t)j*D_ + s*8];
  }
  #pragma unroll
  for (int t=0;t<2;t++){
    int j = (tid>>3) + t*32;
    int d0 = (tid&7)*8;
    bf16x8 qv = *(const bf16x8*)&qg[(size_t)j*D_ + d0];
    unsigned short qb[8];
    #pragma unroll
    for (int i=0;i<8;i++){
      float q = bf2f((unsigned short)qv[i]);
      qb[i] = bf16r((q > 0.f ? 0.02f*q : q) * 0.125f);
    }
    *(uint4*)&q_t[j*PT + d0] = *(uint4*)&qb[0];
    float ev[8] = {0.f,0.f,0.f,0.f,0.f,0.f,0.f,0.f};
    if (c*CHUNK + j < L_-1){
      bf16x8 xv = *(const bf16x8*)&Xbf[(size_t)(row0+j+1)*D_ + h*64 + d0];
      const float4* op = (const float4*)&O1[(size_t)(row0+j)*D_ + h*64 + d0];
      float4 o0 = op[0], o1v = op[1];
      ev[0]=bf2f((unsigned short)xv[0])-o0.x;  ev[1]=bf2f((unsigned short)xv[1])-o0.y;
      ev[2]=bf2f((unsigned short)xv[2])-o0.z;  ev[3]=bf2f((unsigned short)xv[3])-o0.w;
      ev[4]=bf2f((unsigned short)xv[4])-o1v.x; ev[5]=bf2f((unsigned short)xv[5])-o1v.y;
      ev[6]=bf2f((unsigned short)xv[6])-o1v.z; ev[7]=bf2f((unsigned short)xv[7])-o1v.w;
    }
    #pragma unroll
    for (int i=0;i<8;i++) et_t[(d0+i)*PT + j] = bf16r(ev[i]);
  }
  __syncthreads();                                   // B1
  int w = tid>>6, l = tid&63, lr = l&15, g4 = l>>4;
  f32x4 acc[4];
  #pragma unroll
  for (int ni=0;ni<4;ni++) acc[ni] = (f32x4){0.f,0.f,0.f,0.f};
  #pragma unroll
  for (int kk=0;kk<2;kk++){
    bf16x8 a = *(const bf16x8*)&q_t[(w*16+lr)*PT + kk*32 + g4*8];
    #pragma unroll
    for (int ni=0;ni<4;ni++){
      bf16x8 bb = *(const bf16x8*)&k_t[(ni*16+lr)*PT + kk*32 + g4*8];
      acc[ni] = __builtin_amdgcn_mfma_f32_16x16x32_bf16(a, bb, acc[ni], 0,0,0);
    }
  }
  #pragma unroll
  for (int ni=0;ni<4;ni++){
    int j = ni*16 + lr;
    #pragma unroll
    for (int r=0;r<4;r++){
      int row = w*16 + g4*4 + r;
      float v = (j <= row) ? acc[ni][r] : 0.f;
      p_t[row*PT + j] = bf16r(v);
    }
  }
  __syncthreads();                                   // B2: mfma1 k2-reads done
  {
    unsigned short buf[16];
    #pragma unroll
    for (int i=0;i<16;i++) buf[i] = bf16r(carry[i]);
    int row = tid>>2, col = (tid&3)*16;
    *(uint4*)&k_t[row*PT + col]     = *(uint4*)&buf[0];
    *(uint4*)&k_t[row*PT + col + 8] = *(uint4*)&buf[8];
  }
  __syncthreads();                                   // B3
  #pragma unroll
  for (int ni=0;ni<4;ni++) acc[ni] = (f32x4){0.f,0.f,0.f,0.f};
  #pragma unroll
  for (int kk=0;kk<2;kk++){
    bf16x8 ap = *(const bf16x8*)&p_t[(w*16+lr)*PT + kk*32 + g4*8];
    bf16x8 aq = *(const bf16x8*)&q_t[(w*16+lr)*PT + kk*32 + g4*8];
    #pragma unroll
    for (int ni=0;ni<4;ni++){
      bf16x8 be = *(const bf16x8*)&et_t[(ni*16+lr)*PT + kk*32 + g4*8];
      bf16x8 bt = *(const bf16x8*)&k_t[(ni*16+lr)*PT + kk*32 + g4*8];
      acc[ni] = __builtin_amdgcn_mfma_f32_16x16x32_bf16(ap, be, acc[ni], 0,0,0);
      acc[ni] = __builtin_amdgcn_mfma_f32_16x16x32_bf16(aq, bt, acc[ni], 0,0,0);
    }
  }
  __syncthreads();                                   // B4
  #pragma unroll
  for (int ni=0;ni<4;ni++)
    #pragma unroll
    for (int r=0;r<4;r++){
      int row = w*16 + g4*4 + r;
      uni[row*PS + ni*16 + lr] = acc[ni][r];
    }
  __syncthreads();                                   // B5
  #pragma unroll
  for (int t=0;t<4;t++){
    int idx = tid + t*256;
    int r = idx>>4, s = idx&15;
    if (c*CHUNK + r < L_-1) {
      const float4 gv = *(const float4*)&O1[(size_t)(row0+r+1)*D_ + h*64 + s*4];
      float4 uv = *(float4*)&uni[r*PS + s*4];
      ushort4 o;
      o.x = bf16r(gv.x+uv.x); o.y = bf16r(gv.y+uv.y);
      o.z = bf16r(gv.z+uv.z); o.w = bf16r(gv.w+uv.w);
      *(ushort4*)&Obf[(size_t)(row0+r+1)*D_ + h*64 + s*4] = o;
    }
  }
  if (c == 0 && tid < 16) {
    const float4 gv = *(const float4*)&O1[(size_t)row0*D_ + h*64 + tid*4];
    ushort4 o;
    o.x = bf16r(gv.x); o.y = bf16r(gv.y); o.z = bf16r(gv.z); o.w = bf16r(gv.w);
    *(ushort4*)&Obf[(size_t)row0*D_ + h*64 + tid*4] = o;
  }
}

extern "C" void kernel_launch(void* const* d_in, const int* in_sizes, int n_in,
                              void* d_out, int out_size, void* d_ws, size_t ws_size,
                              hipStream_t stream) {
  const float* x  = (const float*)d_in[0];
  const float* Wq = (const float*)d_in[1];
  const float* bq = (const float*)d_in[2];
  const float* Wk1= (const float*)d_in[3];
  const float* bk1= (const float*)d_in[4];
  const float* Wk2= (const float*)d_in[5];
  const float* bk2= (const float*)d_in[6];
  const float* Wg = (const float*)d_in[7];
  const float* bg = (const float*)d_in[8];
  const float* Ws = (const float*)d_in[9];
  const float* bs = (const float*)d_in[10];
  const float* Wp = (const float*)d_in[11];
  const float* bp = (const float*)d_in[12];
  float* out = (float*)d_out;

  float* ws = (float*)d_ws;
  size_t MD = (size_t)M_*D_;
  float* O1b = ws;
  float* CSA = O1b + MD;
  float* CSM = CSA + (size_t)32*NCH*4096;
  float* GLb = CSM + (size_t)32*NCH*4096;
  float* RRb = GLb + (size_t)32*L_;
  unsigned short* Xbf   = (unsigned short*)(RRb + (size_t)32*L_);
  unsigned short* Qbfs  = Xbf  + MD;
  unsigned short* Kbfs  = Qbfs + MD;
  unsigned short* K2bfs = Kbfs + MD;
  unsigned short* Obf   = K2bfs+ MD;
  unsigned short* Wt0   = Obf + MD;
  unsigned short* Wt1   = Wt0 + (size_t)D_*D_;
  unsigned short* Wt2   = Wt1 + (size_t)D_*D_;
  unsigned short* Wt3   = Wt2 + (size_t)D_*D_;

  dim3 gcv(32, 16, 5);
  convert_all<<<gcv, 256, 0, stream>>>(x, Wq, Wk1, Wk2, Wp, Xbf, Wt0, Wt1, Wt2, Wt3);

  dim3 gg(M_/128, D_/128, 3);
  gemm3<<<gg, 256, 0, stream>>>(Xbf, Wt0, Wt1, Wt2, bq, bk1, bk2, Qbfs, Kbfs, K2bfs);

  scalars_kernel<<<(M_*H_)/4, 256, 0, stream>>>(x, Kbfs, Wg, bg, Ws, bs, GLb, RRb);

  dim3 gc(32, NCH);
  ar_chunk_sum<<<gc, 256, 0, stream>>>(Kbfs, Xbf, GLb, RRb, CSA);
  ar_o1_fused<<<gc, 256, 0, stream>>>(Qbfs, Kbfs, Xbf, K2bfs, GLb, RRb, CSA, CSM, O1b);
  ma_o2_mfma<<<gc, 256, 0, stream>>>(Qbfs, K2bfs, Xbf, CSM, O1b, Obf);

  dim3 go(M_/128, D_/64);
  gemm1<<<go, 256, 0, stream>>>(Obf, Wt3, bp, out);
}

// Round 11
// 168.517 us; speedup vs baseline: 1.0992x; 1.0691x over previous
//
#include <hip/hip_runtime.h>
#include <hip/hip_bf16.h>
#include <math.h>

#define B_  2
#define L_  1024
#define D_  1024
#define H_  16
#define DH_ 64
#define M_  (B_*L_)   // 2048
#define CHUNK 64
#define NCH (L_/CHUNK)   // 16
#define PT 72   // bf16 LDS tile pad (shorts)
#define PS 68   // f32 LDS out-stage pad (floats)

#define KSCALE (0.02f/32.0f)   // /sqrt(D) * 0.02

using bf16x8 = __attribute__((ext_vector_type(8))) short;
using f32x4  = __attribute__((ext_vector_type(4))) float;

__device__ __forceinline__ unsigned short bf16r(float f){
  union{float f; unsigned int u;} x; x.f = f;
  unsigned int r = x.u + 0x7FFF + ((x.u>>16)&1);
  return (unsigned short)(r>>16);
}
__device__ __forceinline__ float bf2f(unsigned short u){
  union{unsigned int u; float f;} x; x.u = ((unsigned int)u)<<16; return x.f;
}

// in-wave gate prefix for chunk c of bh. lanes 0..63.
__device__ __forceinline__ void gate_prefix(
  const float* __restrict__ GL, const float* __restrict__ RR,
  int bh, int c, int l, float* cf_s, float* gc_s)
{
  const float* g = GL + (size_t)bh*L_;
  float part = 0.f;
  for (int i = l; i < c*64; i += 64) part += g[i];
  #pragma unroll
  for (int off = 32; off; off >>= 1) part += __shfl_xor(part, off);
  float x = g[c*64 + l];
  #pragma unroll
  for (int off = 1; off < 64; off <<= 1){
    float t = __shfl_up(x, off);
    if (l >= off) x += t;
  }
  float cum = part + x;
  float lc = fminf(fmaxf(cum, -30.f), 30.f);
  float gc = expf(lc) + 1e-6f;
  cf_s[l] = RR[(size_t)bh*L_ + c*64 + l] / gc;
  if (gc_s) gc_s[l] = gc;
}

// chunk-carry (exclusive prefix): 16 consecutive floats/thread
__device__ __forceinline__ void chunk_carry(
  const float* __restrict__ csb, int c, int tid, float* carry)
{
  #pragma unroll
  for (int i=0;i<16;i++) carry[i] = 0.f;
  const float4* cb = (const float4*)(csb + (size_t)tid*16);
  #pragma unroll 2
  for (int c2=0;c2<c;c2++){
    const float4* p4 = cb + (size_t)c2*1024;
    float4 a0=p4[0],a1=p4[1],a2=p4[2],a3=p4[3];
    carry[0]+=a0.x; carry[1]+=a0.y; carry[2]+=a0.z; carry[3]+=a0.w;
    carry[4]+=a1.x; carry[5]+=a1.y; carry[6]+=a1.z; carry[7]+=a1.w;
    carry[8]+=a2.x; carry[9]+=a2.y; carry[10]+=a2.z; carry[11]+=a2.w;
    carry[12]+=a3.x; carry[13]+=a3.y; carry[14]+=a3.z; carry[15]+=a3.w;
  }
}

// ---------------- conversions + GL gate (one launch) ----------------
// z=0..3: W -> Wt bf16 transpose. z=4: x -> bf16 AND GL = log(clip(sigmoid(x_h.Wg+bg)))
__global__ __launch_bounds__(256) void convert_all(
  const float* __restrict__ X,
  const float* __restrict__ W0, const float* __restrict__ W1,
  const float* __restrict__ W2, const float* __restrict__ W3,
  const float* __restrict__ Wg, const float* __restrict__ bg,
  unsigned short* __restrict__ Xbf,
  unsigned short* __restrict__ T0, unsigned short* __restrict__ T1,
  unsigned short* __restrict__ T2, unsigned short* __restrict__ T3,
  float* __restrict__ GL)
{
  int z = blockIdx.z;
  if (z == 4) {
    int r4 = threadIdx.x>>2, cq = threadIdx.x&3;
    int row = blockIdx.x*64 + r4;
    int h = blockIdx.y;
    int col = h*64 + cq*16;
    const float4* src = (const float4*)&X[(size_t)row*D_ + col];
    float4 a=src[0], b=src[1], c=src[2], d=src[3];
    unsigned short buf[16] = {
      bf16r(a.x),bf16r(a.y),bf16r(a.z),bf16r(a.w),
      bf16r(b.x),bf16r(b.y),bf16r(b.z),bf16r(b.w),
      bf16r(c.x),bf16r(c.y),bf16r(c.z),bf16r(c.w),
      bf16r(d.x),bf16r(d.y),bf16r(d.z),bf16r(d.w)};
    *(uint4*)&Xbf[(size_t)row*D_ + col]     = *(uint4*)&buf[0];
    *(uint4*)&Xbf[(size_t)row*D_ + col + 8] = *(uint4*)&buf[8];
    // gate dot over this head's 64 cols (4 lanes per row)
    const float4* wg = (const float4*)&Wg[cq*16];
    float4 w0=wg[0],w1=wg[1],w2=wg[2],w3=wg[3];
    float gd = a.x*w0.x+a.y*w0.y+a.z*w0.z+a.w*w0.w
             + b.x*w1.x+b.y*w1.y+b.z*w1.z+b.w*w1.w
             + c.x*w2.x+c.y*w2.y+c.z*w2.z+c.w*w2.w
             + d.x*w3.x+d.y*w3.y+d.z*w3.z+d.w*w3.w;
    gd += __shfl_xor(gd,1); gd += __shfl_xor(gd,2);
    if (cq == 0){
      int bb = row>>10, ll = row&1023;
      float glogit = gd + bg[0];
      float sg = 1.f/(1.f+expf(-glogit));
      sg = fmaxf(sg, 1e-6f);
      GL[(size_t)(bb*16+h)*L_ + ll] = logf(sg);
    }
    return;
  }
  if (blockIdx.x >= 16) return;
  const float* W = z==0?W0: z==1?W1: z==2?W2: W3;
  unsigned short* T = z==0?T0: z==1?T1: z==2?T2: T3;
  __shared__ float tile[64][65];
  int kBase = blockIdx.x*64, nBase = blockIdx.y*64;
  #pragma unroll
  for (int i=0;i<16;i++){
    int idx = threadIdx.x + i*256;
    int r = idx>>6, c = idx&63;
    tile[r][c] = W[(size_t)(kBase+r)*D_ + nBase+c];
  }
  __syncthreads();
  #pragma unroll
  for (int i=0;i<16;i++){
    int idx = threadIdx.x + i*256;
    int n = idx>>6, k = idx&63;
    T[(size_t)(nBase+n)*D_ + kBase+k] = bf16r(tile[k][n]);
  }
}

// ---------------- 128x128 MFMA GEMM, BK=64: 3 projections (+RR for z==1) ----------------
__global__ __launch_bounds__(256) void gemm3(
  const unsigned short* __restrict__ A,
  const unsigned short* __restrict__ T0, const unsigned short* __restrict__ T1,
  const unsigned short* __restrict__ T2,
  const float* __restrict__ b0, const float* __restrict__ b1, const float* __restrict__ b2,
  const float* __restrict__ Ws, const float* __restrict__ bs,
  unsigned short* __restrict__ F0, unsigned short* __restrict__ F1,
  unsigned short* __restrict__ F2, float* __restrict__ RR)
{
  int z = blockIdx.z;
  const unsigned short* Bt = z==0?T0: z==1?T1: T2;
  const float* bias = z==0?b0: z==1?b1: b2;
  unsigned short* F = z==0?F0: z==1?F1: F2;
  int epi = (z==2) ? 1 : 0;
  int rowBase = blockIdx.x*128, colBase = blockIdx.y*128;

  __shared__ __align__(16) unsigned short As[128*64];
  __shared__ __align__(16) unsigned short Bs[128*64];
  int tid = threadIdx.x, w = tid>>6, l = tid&63;
  int lr = l&15, g4 = l>>4;
  int wr = w>>1, wc = w&1;
  f32x4 acc[4][4];
  #pragma unroll
  for (int mi=0;mi<4;mi++)
    #pragma unroll
    for (int ni=0;ni<4;ni++)
      acc[mi][ni] = (f32x4){0.f,0.f,0.f,0.f};

  for (int k0 = 0; k0 < D_; k0 += 64) {
    #pragma unroll
    for (int i=0;i<4;i++){
      int Fi = (w*4+i)*64 + l;
      int r = Fi>>3, cc = Fi&7;
      int sc = cc ^ (r&7);
      const unsigned short* ga = A  + (size_t)(rowBase+r)*D_ + k0 + sc*8;
      const unsigned short* gb = Bt + (size_t)(colBase+r)*D_ + k0 + sc*8;
      __builtin_amdgcn_global_load_lds(
        (const __attribute__((address_space(1))) void*)ga,
        (__attribute__((address_space(3))) void*)(As + (size_t)(w*4+i)*512), 16, 0, 0);
      __builtin_amdgcn_global_load_lds(
        (const __attribute__((address_space(1))) void*)gb,
        (__attribute__((address_space(3))) void*)(Bs + (size_t)(w*4+i)*512), 16, 0, 0);
    }
    __syncthreads();
    #pragma unroll
    for (int kk=0;kk<2;kk++){
      bf16x8 af[4], bfr[4];
      #pragma unroll
      for (int mi=0;mi<4;mi++){
        int row = wr*64 + mi*16 + lr;
        af[mi] = *(const bf16x8*)(As + row*64 + (((kk*4+g4) ^ (lr&7))<<3));
      }
      #pragma unroll
      for (int ni=0;ni<4;ni++){
        int n = wc*64 + ni*16 + lr;
        bfr[ni] = *(const bf16x8*)(Bs + n*64 + (((kk*4+g4) ^ (lr&7))<<3));
      }
      #pragma unroll
      for (int mi=0;mi<4;mi++)
        #pragma unroll
        for (int ni=0;ni<4;ni++)
          acc[mi][ni] = __builtin_amdgcn_mfma_f32_16x16x32_bf16(af[mi], bfr[ni], acc[mi][ni], 0,0,0);
    }
    __syncthreads();
  }

  float wsv[4];
  if (z==1){
    #pragma unroll
    for (int ni=0;ni<4;ni++) wsv[ni] = Ws[ni*16 + lr];
  }
  float rr[4][4] = {};
  #pragma unroll
  for (int mi=0;mi<4;mi++){
    #pragma unroll
    for (int ni=0;ni<4;ni++){
      int col = colBase + wc*64 + ni*16 + lr;
      float bv = bias[col];
      #pragma unroll
      for (int r=0;r<4;r++){
        int row = rowBase + wr*64 + mi*16 + g4*4 + r;
        float v = acc[mi][ni][r] + bv;
        if (z==1) rr[mi][r] += v * wsv[ni];
        if (epi) v = 1.f/(1.f + expf(-v*KSCALE));
        F[(size_t)row*D_ + col] = bf16r(v);
      }
    }
  }
  if (z==1){
    int h = (colBase>>6) + wc;
    #pragma unroll
    for (int mi=0;mi<4;mi++)
      #pragma unroll
      for (int r=0;r<4;r++){
        float t = rr[mi][r];
        t += __shfl_xor(t,1); t += __shfl_xor(t,2);
        t += __shfl_xor(t,4); t += __shfl_xor(t,8);
        if (lr == 0){
          int row = rowBase + wr*64 + mi*16 + g4*4 + r;
          int bb = row>>10, ll = row&1023;
          float rl = t + bs[0];
          RR[(size_t)(bb*16+h)*L_ + ll] = rl/(1.f+expf(-rl));
        }
      }
  }
}

// ---------------- 128x64 MFMA GEMM, BK=64 (fp32 out): output projection ----------------
__global__ __launch_bounds__(256) void gemm1(
  const unsigned short* __restrict__ A, const unsigned short* __restrict__ Bt,
  const float* __restrict__ bias, float* __restrict__ C)
{
  int rowBase = blockIdx.x*128, colBase = blockIdx.y*64;
  __shared__ __align__(16) unsigned short As[128*64];
  __shared__ __align__(16) unsigned short Bs[64*64];
  int tid = threadIdx.x, w = tid>>6, l = tid&63;
  int lr = l&15, g4 = l>>4;
  f32x4 acc[2][4];
  #pragma unroll
  for (int mi=0;mi<2;mi++)
    #pragma unroll
    for (int ni=0;ni<4;ni++)
      acc[mi][ni] = (f32x4){0.f,0.f,0.f,0.f};

  for (int k0 = 0; k0 < D_; k0 += 64) {
    #pragma unroll
    for (int i=0;i<4;i++){
      int Fi = (w*4+i)*64 + l;
      int r = Fi>>3, cc = Fi&7;
      int sc = cc ^ (r&7);
      const unsigned short* g = A + (size_t)(rowBase+r)*D_ + k0 + sc*8;
      __builtin_amdgcn_global_load_lds(
        (const __attribute__((address_space(1))) void*)g,
        (__attribute__((address_space(3))) void*)(As + (size_t)(w*4+i)*512), 16, 0, 0);
    }
    #pragma unroll
    for (int i=0;i<2;i++){
      int Fi = (w*2+i)*64 + l;
      int r = Fi>>3, cc = Fi&7;
      int sc = cc ^ (r&7);
      const unsigned short* g = Bt + (size_t)(colBase+r)*D_ + k0 + sc*8;
      __builtin_amdgcn_global_load_lds(
        (const __attribute__((address_space(1))) void*)g,
        (__attribute__((address_space(3))) void*)(Bs + (size_t)(w*2+i)*512), 16, 0, 0);
    }
    __syncthreads();
    #pragma unroll
    for (int kk=0;kk<2;kk++){
      bf16x8 af[2], bfr[4];
      #pragma unroll
      for (int mi=0;mi<2;mi++){
        int row = w*32 + mi*16 + lr;
        af[mi] = *(const bf16x8*)(As + row*64 + (((kk*4+g4) ^ (lr&7))<<3));
      }
      #pragma unroll
      for (int ni=0;ni<4;ni++){
        int n = ni*16 + lr;
        bfr[ni] = *(const bf16x8*)(Bs + n*64 + (((kk*4+g4) ^ (lr&7))<<3));
      }
      #pragma unroll
      for (int mi=0;mi<2;mi++)
        #pragma unroll
        for (int ni=0;ni<4;ni++)
          acc[mi][ni] = __builtin_amdgcn_mfma_f32_16x16x32_bf16(af[mi], bfr[ni], acc[mi][ni], 0,0,0);
    }
    __syncthreads();
  }

  #pragma unroll
  for (int mi=0;mi<2;mi++){
    #pragma unroll
    for (int ni=0;ni<4;ni++){
      int col = colBase + ni*16 + lr;
      float bv = bias[col];
      #pragma unroll
      for (int r=0;r<4;r++){
        int row = rowBase + w*32 + mi*16 + g4*4 + r;
        C[(size_t)row*D_ + col] = acc[mi][ni][r] + bv;
      }
    }
  }
}

// ---------------- AR chunk sum (swizzled transposed staging) ----------------
__global__ __launch_bounds__(256) void ar_chunk_sum(
  const unsigned short* __restrict__ Kbf, const unsigned short* __restrict__ Xbf,
  const float* __restrict__ GL, const float* __restrict__ RR,
  float* __restrict__ CS)
{
  int bh = blockIdx.x, c = blockIdx.y;
  int b = bh >> 4, h = bh & 15;
  int row0 = b*L_ + c*CHUNK;
  __shared__ __align__(16) unsigned short kt_t[64*PT];   // K^T swz
  __shared__ __align__(16) unsigned short cv_t[64*PT];   // (cf*V)^T swz
  __shared__ __align__(16) float uni[64*PS];
  __shared__ float cf_s[64];
  int tid = threadIdx.x;
  if (tid < 64) gate_prefix(GL, RR, bh, c, tid, cf_s, nullptr);
  __syncthreads();
  const unsigned short* kg = Kbf + (size_t)row0*D_ + h*64;
  const unsigned short* vg = Xbf + (size_t)row0*D_ + h*64;
  #pragma unroll
  for (int t=0;t<2;t++){
    int j = (tid>>3) + t*32;
    int d0 = (tid&7)*8;
    int col = (((j>>3) ^ (tid&7))<<3) + (j&7);
    bf16x8 kv = *(const bf16x8*)&kg[(size_t)j*D_ + d0];
    bf16x8 vv = *(const bf16x8*)&vg[(size_t)j*D_ + d0];
    float cfj = cf_s[j];
    #pragma unroll
    for (int i=0;i<8;i++){
      kt_t[(d0+i)*PT + col] = (unsigned short)kv[i];
      cv_t[(d0+i)*PT + col] = bf16r(bf2f((unsigned short)vv[i]) * cfj);
    }
  }
  __syncthreads();
  int w = tid>>6, l = tid&63, lr = l&15, g4 = l>>4;
  int ha = (w*2 + (lr>>3)) & 7;   // row>>3 for A rows w*16+lr
  f32x4 acc[4];
  #pragma unroll
  for (int ni=0;ni<4;ni++) acc[ni] = (f32x4){0.f,0.f,0.f,0.f};
  #pragma unroll
  for (int kk=0;kk<2;kk++){
    bf16x8 a = *(const bf16x8*)&cv_t[(w*16+lr)*PT + (((kk*4+g4) ^ ha)<<3)];
    #pragma unroll
    for (int ni=0;ni<4;ni++){
      int hb = (ni*2 + (lr>>3)) & 7;
      bf16x8 bb = *(const bf16x8*)&kt_t[(ni*16+lr)*PT + (((kk*4+g4) ^ hb)<<3)];
      acc[ni] = __builtin_amdgcn_mfma_f32_16x16x32_bf16(a, bb, acc[ni], 0,0,0);
    }
  }
  #pragma unroll
  for (int ni=0;ni<4;ni++)
    #pragma unroll
    for (int r=0;r<4;r++)
      uni[(w*16+g4*4+r)*PS + ni*16+lr] = acc[ni][r];
  __syncthreads();
  float* out = CS + ((size_t)bh*NCH + c)*4096;
  #pragma unroll
  for (int t=0;t<4;t++){
    int idx = tid + t*256;
    int r = idx>>4, s = idx&15;
    *(float4*)&out[r*64 + s*4] = *(float4*)&uni[r*PS + s*4];
  }
}

// ---------------- fused AR O1 + MA chunk sum ----------------
__global__ __launch_bounds__(256) void ar_o1_fused(
  const unsigned short* __restrict__ Qbf, const unsigned short* __restrict__ Kbf,
  const unsigned short* __restrict__ Xbf, const unsigned short* __restrict__ K2bf,
  const float* __restrict__ GL, const float* __restrict__ RR,
  const float* __restrict__ CSA, float* __restrict__ CSM,
  float* __restrict__ O1)
{
  int bh = blockIdx.x, c = blockIdx.y;
  int b = bh >> 4, h = bh & 15;
  int row0 = b*L_ + c*CHUNK;
  __shared__ __align__(16) unsigned short q_t[64*PT];    // Q row-major
  __shared__ __align__(16) unsigned short k_t[64*PT];    // K row-major -> carry -> E^T swz
  __shared__ __align__(16) unsigned short vt_t[64*PT];   // V^T swz -> k2^T swz
  __shared__ __align__(16) float uni[64*PS];
  unsigned short* p_t = (unsigned short*)uni;
  __shared__ float cf_s[64], gc_s[64];
  int tid = threadIdx.x;
  if (tid < 64) gate_prefix(GL, RR, bh, c, tid, cf_s, gc_s);
  const unsigned short* qg = Qbf + (size_t)row0*D_ + h*64;
  const unsigned short* kg = Kbf + (size_t)row0*D_ + h*64;
  const unsigned short* vg = Xbf + (size_t)row0*D_ + h*64;
  float carry[16];
  chunk_carry(CSA + (size_t)bh*NCH*4096, c, tid, carry);
  #pragma unroll
  for (int t=0;t<2;t++){
    int idx = tid + t*256;
    int j = idx>>3, s = idx&7;
    *(uint4*)&q_t[j*PT + s*8] = *(const uint4*)&qg[(size_t)j*D_ + s*8];
    *(uint4*)&k_t[j*PT + s*8] = *(const uint4*)&kg[(size_t)j*D_ + s*8];
  }
  #pragma unroll
  for (int t=0;t<2;t++){
    int j = (tid>>3) + t*32;
    int e0 = (tid&7)*8;
    int col = (((j>>3) ^ (tid&7))<<3) + (j&7);
    bf16x8 vv = *(const bf16x8*)&vg[(size_t)j*D_ + e0];
    #pragma unroll
    for (int i=0;i<8;i++) vt_t[(e0+i)*PT + col] = (unsigned short)vv[i];
  }
  __syncthreads();                                   // B1
  int w = tid>>6, l = tid&63, lr = l&15, g4 = l>>4;
  int ha = (w*2 + (lr>>3)) & 7;
  // mfma1: P = causal(Q @ K^T) * cf  (q_t/k_t plain)
  f32x4 acc[4];
  #pragma unroll
  for (int ni=0;ni<4;ni++) acc[ni] = (f32x4){0.f,0.f,0.f,0.f};
  #pragma unroll
  for (int kk=0;kk<2;kk++){
    bf16x8 a = *(const bf16x8*)&q_t[(w*16+lr)*PT + kk*32 + g4*8];
    #pragma unroll
    for (int ni=0;ni<4;ni++){
      bf16x8 bb = *(const bf16x8*)&k_t[(ni*16+lr)*PT + kk*32 + g4*8];
      acc[ni] = __builtin_amdgcn_mfma_f32_16x16x32_bf16(a, bb, acc[ni], 0,0,0);
    }
  }
  #pragma unroll
  for (int ni=0;ni<4;ni++){
    int j = ni*16 + lr;
    float cf = cf_s[j];
    #pragma unroll
    for (int r=0;r<4;r++){
      int row = w*16 + g4*4 + r;
      float v = (j <= row) ? acc[ni][r]*cf : 0.f;
      p_t[row*PT + j] = bf16r(v);
    }
  }
  __syncthreads();                                   // B2
  {
    unsigned short buf[16];
    #pragma unroll
    for (int i=0;i<16;i++) buf[i] = bf16r(carry[i]);
    int row = tid>>2, col = (tid&3)*16;
    *(uint4*)&k_t[row*PT + col]     = *(uint4*)&buf[0];
    *(uint4*)&k_t[row*PT + col + 8] = *(uint4*)&buf[8];
  }
  __syncthreads();                                   // B3
  // mfma2: O1 = Gc*(P@V + Q@Sc^T)  (vt_t swz; k_t carry plain)
  #pragma unroll
  for (int ni=0;ni<4;ni++) acc[ni] = (f32x4){0.f,0.f,0.f,0.f};
  #pragma unroll
  for (int kk=0;kk<2;kk++){
    bf16x8 ap = *(const bf16x8*)&p_t[(w*16+lr)*PT + kk*32 + g4*8];
    bf16x8 aq = *(const bf16x8*)&q_t[(w*16+lr)*PT + kk*32 + g4*8];
    #pragma unroll
    for (int ni=0;ni<4;ni++){
      int hb = (ni*2 + (lr>>3)) & 7;
      bf16x8 bv = *(const bf16x8*)&vt_t[(ni*16+lr)*PT + (((kk*4+g4) ^ hb)<<3)];
      bf16x8 bs = *(const bf16x8*)&k_t[(ni*16+lr)*PT + kk*32 + g4*8];
      acc[ni] = __builtin_amdgcn_mfma_f32_16x16x32_bf16(ap, bv, acc[ni], 0,0,0);
      acc[ni] = __builtin_amdgcn_mfma_f32_16x16x32_bf16(aq, bs, acc[ni], 0,0,0);
    }
  }
  __syncthreads();                                   // B4
  #pragma unroll
  for (int ni=0;ni<4;ni++)
    #pragma unroll
    for (int r=0;r<4;r++){
      int row = w*16 + g4*4 + r;
      uni[row*PS + ni*16 + lr] = gc_s[row]*acc[ni][r];
    }
  __syncthreads();                                   // B5: uni = fp32 O1
  #pragma unroll
  for (int t=0;t<4;t++){
    int idx = tid + t*256;
    int r = idx>>4, s = idx&15;
    *(float4*)&O1[(size_t)(row0+r)*D_ + h*64 + s*4] = *(float4*)&uni[r*PS + s*4];
  }
  #pragma unroll
  for (int t=0;t<2;t++){
    int j = (tid>>3) + t*32;
    int d0 = (tid&7)*8;
    int col = (((j>>3) ^ (tid&7))<<3) + (j&7);
    bf16x8 kv = *(const bf16x8*)&K2bf[(size_t)(row0+j)*D_ + h*64 + d0];
    float ev[8] = {0.f,0.f,0.f,0.f,0.f,0.f,0.f,0.f};
    if (c*CHUNK + j < L_-1){
      bf16x8 xv = *(const bf16x8*)&Xbf[(size_t)(row0+j+1)*D_ + h*64 + d0];
      const float4* up = (const float4*)&uni[j*PS + d0];
      float4 u0 = up[0], u1 = up[1];
      ev[0]=bf2f((unsigned short)xv[0])-u0.x; ev[1]=bf2f((unsigned short)xv[1])-u0.y;
      ev[2]=bf2f((unsigned short)xv[2])-u0.z; ev[3]=bf2f((unsigned short)xv[3])-u0.w;
      ev[4]=bf2f((unsigned short)xv[4])-u1.x; ev[5]=bf2f((unsigned short)xv[5])-u1.y;
      ev[6]=bf2f((unsigned short)xv[6])-u1.z; ev[7]=bf2f((unsigned short)xv[7])-u1.w;
    }
    #pragma unroll
    for (int i=0;i<8;i++){
      vt_t[(d0+i)*PT + col] = (unsigned short)kv[i];   // k2^T swz
      k_t [(d0+i)*PT + col] = bf16r(ev[i]);            // E^T swz
    }
  }
  __syncthreads();                                   // B6
  // MA chunk sum (both operands swizzled)
  f32x4 acc2[4];
  #pragma unroll
  for (int ni=0;ni<4;ni++) acc2[ni] = (f32x4){0.f,0.f,0.f,0.f};
  #pragma unroll
  for (int kk=0;kk<2;kk++){
    bf16x8 a = *(const bf16x8*)&k_t[(w*16+lr)*PT + (((kk*4+g4) ^ ha)<<3)];
    #pragma unroll
    for (int ni=0;ni<4;ni++){
      int hb = (ni*2 + (lr>>3)) & 7;
      bf16x8 bb = *(const bf16x8*)&vt_t[(ni*16+lr)*PT + (((kk*4+g4) ^ hb)<<3)];
      acc2[ni] = __builtin_amdgcn_mfma_f32_16x16x32_bf16(a, bb, acc2[ni], 0,0,0);
    }
  }
  __syncthreads();                                   // B7
  #pragma unroll
  for (int ni=0;ni<4;ni++)
    #pragma unroll
    for (int r=0;r<4;r++)
      uni[(w*16+g4*4+r)*PS + ni*16+lr] = acc2[ni][r];
  __syncthreads();                                   // B8
  float* outm = CSM + ((size_t)bh*NCH + c)*4096;
  #pragma unroll
  for (int t=0;t<4;t++){
    int idx = tid + t*256;
    int r = idx>>4, s = idx&15;
    *(float4*)&outm[r*64 + s*4] = *(float4*)&uni[r*PS + s*4];
  }
}

// ---------------- MA O2 per chunk; writes final bf16 O ----------------
__global__ __launch_bounds__(256) void ma_o2_mfma(
  const unsigned short* __restrict__ Qbf, const unsigned short* __restrict__ K2bf,
  const unsigned short* __restrict__ Xbf, const float* __restrict__ CS,
  const float* __restrict__ O1, unsigned short* __restrict__ Obf)
{
  int bh = blockIdx.x, c = blockIdx.y;
  int b = bh >> 4, h = bh & 15;
  int row0 = b*L_ + c*CHUNK;
  __shared__ __align__(16) unsigned short q_t[64*PT];    // q2 row-major
  __shared__ __align__(16) unsigned short k_t[64*PT];    // k2 row-major -> carry
  __shared__ __align__(16) unsigned short et_t[64*PT];   // E^T swz
  __shared__ __align__(16) float uni[64*PS];
  unsigned short* p_t = (unsigned short*)uni;
  int tid = threadIdx.x;
  const unsigned short* qg = Qbf  + (size_t)row0*D_ + h*64;
  const unsigned short* kg = K2bf + (size_t)row0*D_ + h*64;
  float carry[16];
  chunk_carry(CS + (size_t)bh*NCH*4096, c, tid, carry);
  #pragma unroll
  for (int t=0;t<2;t++){
    int idx = tid + t*256;
    int j = idx>>3, s = idx&7;
    *(uint4*)&k_t[j*PT + s*8] = *(const uint4*)&kg[(size_t)j*D_ + s*8];
  }
  #pragma unroll
  for (int t=0;t<2;t++){
    int j = (tid>>3) + t*32;
    int d0 = (tid&7)*8;
    int col = (((j>>3) ^ (tid&7))<<3) + (j&7);
    bf16x8 qv = *(const bf16x8*)&qg[(size_t)j*D_ + d0];
    unsigned short qb[8];
    #pragma unroll
    for (int i=0;i<8;i++){
      float q = bf2f((unsigned short)qv[i]);
      qb[i] = bf16r((q > 0.f ? 0.02f*q : q) * 0.125f);
    }
    *(uint4*)&q_t[j*PT + d0] = *(uint4*)&qb[0];
    float ev[8] = {0.f,0.f,0.f,0.f,0.f,0.f,0.f,0.f};
    if (c*CHUNK + j < L_-1){
      bf16x8 xv = *(const bf16x8*)&Xbf[(size_t)(row0+j+1)*D_ + h*64 + d0];
      const float4* op = (const float4*)&O1[(size_t)(row0+j)*D_ + h*64 + d0];
      float4 o0 = op[0], o1v = op[1];
      ev[0]=bf2f((unsigned short)xv[0])-o0.x;  ev[1]=bf2f((unsigned short)xv[1])-o0.y;
      ev[2]=bf2f((unsigned short)xv[2])-o0.z;  ev[3]=bf2f((unsigned short)xv[3])-o0.w;
      ev[4]=bf2f((unsigned short)xv[4])-o1v.x; ev[5]=bf2f((unsigned short)xv[5])-o1v.y;
      ev[6]=bf2f((unsigned short)xv[6])-o1v.z; ev[7]=bf2f((unsigned short)xv[7])-o1v.w;
    }
    #pragma unroll
    for (int i=0;i<8;i++) et_t[(d0+i)*PT + col] = bf16r(ev[i]);
  }
  __syncthreads();                                   // B1
  int w = tid>>6, l = tid&63, lr = l&15, g4 = l>>4;
  f32x4 acc[4];
  #pragma unroll
  for (int ni=0;ni<4;ni++) acc[ni] = (f32x4){0.f,0.f,0.f,0.f};
  #pragma unroll
  for (int kk=0;kk<2;kk++){
    bf16x8 a = *(const bf16x8*)&q_t[(w*16+lr)*PT + kk*32 + g4*8];
    #pragma unroll
    for (int ni=0;ni<4;ni++){
      bf16x8 bb = *(const bf16x8*)&k_t[(ni*16+lr)*PT + kk*32 + g4*8];
      acc[ni] = __builtin_amdgcn_mfma_f32_16x16x32_bf16(a, bb, acc[ni], 0,0,0);
    }
  }
  #pragma unroll
  for (int ni=0;ni<4;ni++){
    int j = ni*16 + lr;
    #pragma unroll
    for (int r=0;r<4;r++){
      int row = w*16 + g4*4 + r;
      float v = (j <= row) ? acc[ni][r] : 0.f;
      p_t[row*PT + j] = bf16r(v);
    }
  }
  __syncthreads();                                   // B2
  {
    unsigned short buf[16];
    #pragma unroll
    for (int i=0;i<16;i++) buf[i] = bf16r(carry[i]);
    int row = tid>>2, col = (tid&3)*16;
    *(uint4*)&k_t[row*PT + col]     = *(uint4*)&buf[0];
    *(uint4*)&k_t[row*PT + col + 8] = *(uint4*)&buf[8];
  }
  __syncthreads();                                   // B3
  #pragma unroll
  for (int ni=0;ni<4;ni++) acc[ni] = (f32x4){0.f,0.f,0.f,0.f};
  #pragma unroll
  for (int kk=0;kk<2;kk++){
    bf16x8 ap = *(const bf16x8*)&p_t[(w*16+lr)*PT + kk*32 + g4*8];
    bf16x8 aq = *(const bf16x8*)&q_t[(w*16+lr)*PT + kk*32 + g4*8];
    #pragma unroll
    for (int ni=0;ni<4;ni++){
      int hb = (ni*2 + (lr>>3)) & 7;
      bf16x8 be = *(const bf16x8*)&et_t[(ni*16+lr)*PT + (((kk*4+g4) ^ hb)<<3)];
      bf16x8 bt = *(const bf16x8*)&k_t[(ni*16+lr)*PT + kk*32 + g4*8];
      acc[ni] = __builtin_amdgcn_mfma_f32_16x16x32_bf16(ap, be, acc[ni], 0,0,0);
      acc[ni] = __builtin_amdgcn_mfma_f32_16x16x32_bf16(aq, bt, acc[ni], 0,0,0);
    }
  }
  __syncthreads();                                   // B4
  #pragma unroll
  for (int ni=0;ni<4;ni++)
    #pragma unroll
    for (int r=0;r<4;r++){
      int row = w*16 + g4*4 + r;
      uni[row*PS + ni*16 + lr] = acc[ni][r];
    }
  __syncthreads();                                   // B5
  #pragma unroll
  for (int t=0;t<4;t++){
    int idx = tid + t*256;
    int r = idx>>4, s = idx&15;
    if (c*CHUNK + r < L_-1) {
      const float4 gv = *(const float4*)&O1[(size_t)(row0+r+1)*D_ + h*64 + s*4];
      float4 uv = *(float4*)&uni[r*PS + s*4];
      ushort4 o;
      o.x = bf16r(gv.x+uv.x); o.y = bf16r(gv.y+uv.y);
      o.z = bf16r(gv.z+uv.z); o.w = bf16r(gv.w+uv.w);
      *(ushort4*)&Obf[(size_t)(row0+r+1)*D_ + h*64 + s*4] = o;
    }
  }
  if (c == 0 && tid < 16) {
    const float4 gv = *(const float4*)&O1[(size_t)row0*D_ + h*64 + tid*4];
    ushort4 o;
    o.x = bf16r(gv.x); o.y = bf16r(gv.y); o.z = bf16r(gv.z); o.w = bf16r(gv.w);
    *(ushort4*)&Obf[(size_t)row0*D_ + h*64 + tid*4] = o;
  }
}

extern "C" void kernel_launch(void* const* d_in, const int* in_sizes, int n_in,
                              void* d_out, int out_size, void* d_ws, size_t ws_size,
                              hipStream_t stream) {
  const float* x  = (const float*)d_in[0];
  const float* Wq = (const float*)d_in[1];
  const float* bq = (const float*)d_in[2];
  const float* Wk1= (const float*)d_in[3];
  const float* bk1= (const float*)d_in[4];
  const float* Wk2= (const float*)d_in[5];
  const float* bk2= (const float*)d_in[6];
  const float* Wg = (const float*)d_in[7];
  const float* bg = (const float*)d_in[8];
  const float* Ws = (const float*)d_in[9];
  const float* bs = (const float*)d_in[10];
  const float* Wp = (const float*)d_in[11];
  const float* bp = (const float*)d_in[12];
  float* out = (float*)d_out;

  float* ws = (float*)d_ws;
  size_t MD = (size_t)M_*D_;
  float* O1b = ws;
  float* CSA = O1b + MD;
  float* CSM = CSA + (size_t)32*NCH*4096;
  float* GLb = CSM + (size_t)32*NCH*4096;
  float* RRb = GLb + (size_t)32*L_;
  unsigned short* Xbf   = (unsigned short*)(RRb + (size_t)32*L_);
  unsigned short* Qbfs  = Xbf  + MD;
  unsigned short* Kbfs  = Qbfs + MD;
  unsigned short* K2bfs = Kbfs + MD;
  unsigned short* Obf   = K2bfs+ MD;
  unsigned short* Wt0   = Obf + MD;
  unsigned short* Wt1   = Wt0 + (size_t)D_*D_;
  unsigned short* Wt2   = Wt1 + (size_t)D_*D_;
  unsigned short* Wt3   = Wt2 + (size_t)D_*D_;

  dim3 gcv(32, 16, 5);
  convert_all<<<gcv, 256, 0, stream>>>(x, Wq, Wk1, Wk2, Wp, Wg, bg,
                                       Xbf, Wt0, Wt1, Wt2, Wt3, GLb);

  dim3 gg(M_/128, D_/128, 3);
  gemm3<<<gg, 256, 0, stream>>>(Xbf, Wt0, Wt1, Wt2, bq, bk1, bk2, Ws, bs,
                                Qbfs, Kbfs, K2bfs, RRb);

  dim3 gc(32, NCH);
  ar_chunk_sum<<<gc, 256, 0, stream>>>(Kbfs, Xbf, GLb, RRb, CSA);
  ar_o1_fused<<<gc, 256, 0, stream>>>(Qbfs, Kbfs, Xbf, K2bfs, GLb, RRb, CSA, CSM, O1b);
  ma_o2_mfma<<<gc, 256, 0, stream>>>(Qbfs, K2bfs, Xbf, CSM, O1b, Obf);

  dim3 go(M_/128, D_/64);
  gemm1<<<go, 256, 0, stream>>>(Obf, Wt3, bp, out);
}